// Round 1
// baseline (352.183 us; speedup 1.0000x reference)
//
#include <hip/hip_runtime.h>

// B=4, C=256, H=W=64 (N=4096). QKV 1x1conv -> spatial attention (softmax over
// j only => independent per-64-key-chunk softmax) -> channel LayerNorm.
// f16 MFMA 32x32x16, fp32 accumulation.
//
// R7: attn decomposed into 4 INDEPENDENT 256-thread blocks per (b,qtile)
// (grid 1024), each handling 16 key-chunks with private Ss/Ps and its own
// barriers -> co-resident blocks overlap softmax(VALU) with MFMA instead of
// the R6 phase-lockstep. Ks LDS staging removed (K fragments streamed from
// global/L2, same addressing as before) -> LDS 125KB -> 26.6KB, one fewer
// barrier per chunk, kreg freed. launch_bounds(256,3) targets 3 waves/SIMD.
// Blocks emit partial F (fp32) to workspace; merge_ln_kernel sums the 4
// partials and applies fused LayerNorm. prep/gemm identical to R6.

#define CDIM 256
#define NPOS 4096
#define BATCH 4
#define EPSV 1e-5f

typedef _Float16 f16;
typedef __attribute__((ext_vector_type(8))) _Float16 f16x8;
typedef __attribute__((ext_vector_type(4))) float f32x4;
typedef __attribute__((ext_vector_type(16))) float f32x16;

#define WST       264   // f16; 528B = 33*16 -> b128-aligned rows
#define S_STRIDE  68    // f32; 272B = 17*16
#define P_STRIDE  72
#define DQ_STRIDE 72
#define F_STRIDE  68    // merge kernel LDS stride (f32)

// MFMA 32x32x16 f16:
//   A: lane l holds A[m=l&31][k=(l>>5)*8+j]
//   B: lane l holds B[k=(l>>5)*8+j][n=l&31]
//   C/D: lane l, reg r -> col=l&31, row=(r&3)+8*(r>>2)+4*(l>>5)

static __device__ __forceinline__ f16x8 cvt8(const float* __restrict__ p) {
    float4 w0 = *(const float4*)p;
    float4 w1 = *(const float4*)(p + 4);
    f16x8 r;
    r[0] = (f16)w0.x; r[1] = (f16)w0.y; r[2] = (f16)w0.z; r[3] = (f16)w0.w;
    r[4] = (f16)w1.x; r[5] = (f16)w1.y; r[6] = (f16)w1.z; r[7] = (f16)w1.w;
    return r;
}

// ---------------------------------------------------------------------------
// prep: blocks 0..2047 transpose x1/x2 [C][N] fp32 -> [N][C] f16 (64x64 tiles);
// blocks 2048..2059 convert weights fp32 -> f16 [o][c].  (unchanged)
// ---------------------------------------------------------------------------
__global__ __launch_bounds__(256, 4) void prep_kernel(
    const float* __restrict__ x1, const float* __restrict__ x2,
    const float* __restrict__ qw, const float* __restrict__ kw,
    const float* __restrict__ vw,
    f16* __restrict__ X1T, f16* __restrict__ X2T, f16* __restrict__ W16)
{
    const int id = blockIdx.x;
    const int t  = threadIdx.x;
    if (id < 2048) {
        __shared__ f16 T[64 * 72];
        const float* xs = (id & 1) ? x2 : x1;
        f16* dst        = (id & 1) ? X2T : X1T;
        const int t2 = id >> 1;
        const int b  = t2 >> 8;
        const int rm = t2 & 255;
        const int c0 = (rm >> 6) * 64;
        const int n0 = (rm & 63) * 64;
        const float* src = xs + ((size_t)b * CDIM + c0) * NPOS + n0;
        const int rr = t >> 6, col = t & 63;
        #pragma unroll
        for (int j = 0; j < 16; ++j) {
            int row = rr + j * 4;
            T[col * 72 + row] = (f16)src[(size_t)row * NPOS + col];
        }
        __syncthreads();
        const int n = t >> 3, lc = (t & 7) * 8;
        f16* d0 = dst + ((size_t)b * NPOS + n0) * CDIM + c0;
        #pragma unroll
        for (int j = 0; j < 2; ++j) {
            int nn = n + j * 32;
            *(f16x8*)(d0 + (size_t)nn * CDIM + lc) = *(const f16x8*)&T[nn * 72 + lc];
        }
    } else {
        const int wblk = id - 2048;          // 0..11
        const int pr = wblk >> 2, h = wblk & 3;
        const float* W = (pr == 0 ? qw : pr == 1 ? kw : vw) + (size_t)h * 64 * CDIM;
        f16* D = W16 + (size_t)pr * CDIM * CDIM + (size_t)h * 64 * CDIM;
        #pragma unroll
        for (int i = 0; i < 8; ++i) {
            int g = t + i * 256;
            int row = g >> 5, col = (g & 31) * 8;
            *(f16x8*)(D + (size_t)row * CDIM + col) = cvt8(W + (size_t)row * CDIM + col);
        }
    }
}

// ---------------------------------------------------------------------------
// gemm: unchanged (proven correct). 768 blocks, weight quarters in LDS,
// split-k dual acc, LDS-assisted coalesced stores.
// ---------------------------------------------------------------------------
__global__ __launch_bounds__(256, 2) void gemm_kernel(
    const f16* __restrict__ X1T, const f16* __restrict__ X2T,
    const f16* __restrict__ W16,
    const float* __restrict__ qb, const float* __restrict__ kb,
    const float* __restrict__ vb,
    f16* __restrict__ Qg, f16* __restrict__ Kg, f16* __restrict__ Vg)
{
    __shared__ f16 Xs[64 * WST];
    __shared__ f16 Wh[64 * WST];
    __shared__ f16 Ds[64 * DQ_STRIDE];
    __shared__ float biasS[256];

    const int id = blockIdx.x;
    const int pr  = id >> 8;
    const int rem = id & 255;
    const int b   = rem >> 6;
    const int p0  = (rem & 63) << 6;
    const f16* XT = (pr == 0) ? X1T : X2T;
    const f16* Wp = W16 + (size_t)pr * CDIM * CDIM;
    const float* bias = pr == 0 ? qb : pr == 1 ? kb : vb;

    const int t = threadIdx.x, w = t >> 6, l = t & 63, lm = l & 31, lh = l >> 5;
    const int pt = w & 1, ot = w >> 1;

    biasS[t] = bias[t];
    #pragma unroll
    for (int it = 0; it < 8; ++it) {
        int p = w * 16 + it * 2 + lh;
        *(f16x8*)&Xs[p * WST + lm * 8] =
            *(const f16x8*)(XT + ((size_t)(b * NPOS + p0 + p)) * CDIM + lm * 8);
    }

    for (int q = 0; q < 4; ++q) {
        #pragma unroll
        for (int i = 0; i < 8; ++i) {
            int g = t + i * 256;
            int row = g >> 5, col = (g & 31) * 8;
            *(f16x8*)&Wh[row * WST + col] =
                *(const f16x8*)(Wp + (size_t)(q * 64 + row) * CDIM + col);
        }
        __syncthreads();

        f32x16 accA = {}, accB = {};
        #pragma unroll
        for (int ks = 0; ks < 16; ks += 2) {
            f16x8 x0 = *(const f16x8*)&Xs[(pt * 32 + lm) * WST + ks * 16 + lh * 8];
            f16x8 w0 = *(const f16x8*)&Wh[(ot * 32 + lm) * WST + ks * 16 + lh * 8];
            f16x8 x1v = *(const f16x8*)&Xs[(pt * 32 + lm) * WST + (ks + 1) * 16 + lh * 8];
            f16x8 w1 = *(const f16x8*)&Wh[(ot * 32 + lm) * WST + (ks + 1) * 16 + lh * 8];
            if (pr < 2) {
                accA = __builtin_amdgcn_mfma_f32_32x32x16_f16(x0, w0, accA, 0, 0, 0);
                accB = __builtin_amdgcn_mfma_f32_32x32x16_f16(x1v, w1, accB, 0, 0, 0);
            } else {
                accA = __builtin_amdgcn_mfma_f32_32x32x16_f16(w0, x0, accA, 0, 0, 0);
                accB = __builtin_amdgcn_mfma_f32_32x32x16_f16(w1, x1v, accB, 0, 0, 0);
            }
        }

        if (pr < 2) {
            int o_l = ot * 32 + lm;
            float bv = biasS[q * 64 + o_l];
            #pragma unroll
            for (int r = 0; r < 16; ++r) {
                int p_l = pt * 32 + (r & 3) + 8 * (r >> 2) + 4 * lh;
                Ds[p_l * DQ_STRIDE + o_l] = (f16)(accA[r] + accB[r] + bv);
            }
        } else {
            #pragma unroll
            for (int r = 0; r < 16; ++r) {
                int o_l = ot * 32 + (r & 3) + 8 * (r >> 2) + 4 * lh;
                Ds[o_l * DQ_STRIDE + pt * 32 + lm] =
                    (f16)(accA[r] + accB[r] + biasS[q * 64 + o_l]);
            }
        }
        __syncthreads();

        #pragma unroll
        for (int j = 0; j < 2; ++j) {
            int row = (t >> 3) + j * 32;
            int cc  = (t & 7) * 8;
            f16x8 vdat = *(const f16x8*)&Ds[row * DQ_STRIDE + cc];
            if (pr < 2) {
                f16* Out = (pr == 0) ? Qg : Kg;
                *(f16x8*)(Out + ((size_t)(b * NPOS + p0 + row)) * CDIM + q * 64 + cc) = vdat;
            } else {
                *(f16x8*)(Vg + ((size_t)(b * CDIM + q * 64 + row)) * NPOS + p0 + cc) = vdat;
            }
        }
        __syncthreads();
    }
}

// ---------------------------------------------------------------------------
// attn: grid 1024 = ((b<<6 | qtile)<<2 | quarter), 256 thr = 4 waves.
// Each block: 16 key-chunks (quarter*16 + it), private Ss/Ps, 2 barriers per
// chunk. K and V fragments streamed from global (L2-resident). Emits partial
// F fp32 [bq][quarter][256c][64p]; no LN here. LDS ~26.6 KB.
// ---------------------------------------------------------------------------
__global__ __launch_bounds__(256, 3) void attn_kernel(
    const f16* __restrict__ Qg, const f16* __restrict__ Kg, const f16* __restrict__ Vg,
    float* __restrict__ Fp)
{
    __shared__ float Ss[64 * S_STRIDE];   // 17408 B
    __shared__ f16   Ps[64 * P_STRIDE];   //  9216 B

    const int t   = threadIdx.x;
    const int qtr = blockIdx.x & 3;
    const int bq  = blockIdx.x >> 2;
    const int b   = bq >> 6;
    const int p0  = (bq & 63) << 6;
    const int w   = t >> 6;          // 0..3
    const int l   = t & 63;
    const int lm  = l & 31;
    const int lh  = l >> 5;
    const int spt = w & 1;           // wave's S tile: query-tile spt, key-tile skt
    const int skt = w >> 1;

    // Q fragments for this wave's query-tile (held in registers for all chunks)
    f16x8 qf[16];
    {
        const f16* qptr = Qg + (size_t)(b * NPOS + p0 + spt * 32 + lm) * CDIM + lh * 8;
        #pragma unroll
        for (int ks = 0; ks < 16; ++ks) qf[ks] = *(const f16x8*)(qptr + ks * 16);
    }

    // V fragment bases: wave's c-strip = w*64 + {0,32}
    const f16* vb0 = Vg + (size_t)(b * CDIM + w * 64 + lm) * NPOS;
    const f16* vb1 = Vg + (size_t)(b * CDIM + w * 64 + 32 + lm) * NPOS;

    f32x16 facc[4] = {};      // per-wave F acc: [i=c-tile(2)][j=p-tile(2)]

    for (int it = 0; it < 16; ++it) {
        const int i0 = (qtr * 16 + it) * 64;

        // S = Q K^T ; K fragments streamed from global (same addresses the
        // old LDS staging produced; chunk is L2-resident)
        const f16* kp = Kg + (size_t)(b * NPOS + i0 + skt * 32 + lm) * CDIM + lh * 8;
        f32x16 sacc = {};
        #pragma unroll
        for (int ks = 0; ks < 16; ++ks) {
            f16x8 bb = *(const f16x8*)(kp + ks * 16);
            sacc = __builtin_amdgcn_mfma_f32_32x32x16_f16(qf[ks], bb, sacc, 0, 0, 0);
        }
        #pragma unroll
        for (int r = 0; r < 16; ++r) {
            int row = (r & 3) + 8 * (r >> 2) + 4 * lh;
            Ss[(spt * 32 + row) * S_STRIDE + skt * 32 + lm] = sacc[r];
        }
        __syncthreads();   // A: Ss ready (also: prev iter's Ps reads all done)

        // softmax per row: 4 threads/row x 16 elems
        {
            const int r  = t >> 2;
            const int sg = (t & 3) * 16;
            const float* srow = &Ss[r * S_STRIDE + sg];
            float v[16];
            f32x4 a0 = *(const f32x4*)(srow);
            f32x4 a1 = *(const f32x4*)(srow + 4);
            f32x4 a2 = *(const f32x4*)(srow + 8);
            f32x4 a3 = *(const f32x4*)(srow + 12);
            v[0]=a0[0]; v[1]=a0[1]; v[2]=a0[2]; v[3]=a0[3];
            v[4]=a1[0]; v[5]=a1[1]; v[6]=a1[2]; v[7]=a1[3];
            v[8]=a2[0]; v[9]=a2[1]; v[10]=a2[2]; v[11]=a2[3];
            v[12]=a3[0]; v[13]=a3[1]; v[14]=a3[2]; v[15]=a3[3];
            float m = v[0];
            #pragma unroll
            for (int i = 1; i < 16; ++i) m = fmaxf(m, v[i]);
            m = fmaxf(m, __shfl_xor(m, 1));
            m = fmaxf(m, __shfl_xor(m, 2));
            float s = 0.f;
            #pragma unroll
            for (int i = 0; i < 16; ++i) { float e = __expf(v[i] - m); v[i] = e; s += e; }
            s += __shfl_xor(s, 1);
            s += __shfl_xor(s, 2);
            float inv = __builtin_amdgcn_rcpf(s);
            f16x8 h0, h1;
            #pragma unroll
            for (int i = 0; i < 8; ++i) { h0[i] = (f16)(v[i] * inv); h1[i] = (f16)(v[i + 8] * inv); }
            *(f16x8*)&Ps[r * P_STRIDE + sg]     = h0;
            *(f16x8*)&Ps[r * P_STRIDE + sg + 8] = h1;
        }
        __syncthreads();   // B: Ps ready (also: Ss reads done before next S writes)

        // F += V * P^T   (V fragments loaded inside loop to cap liveness)
        #pragma unroll
        for (int ks = 0; ks < 4; ++ks) {
            f16x8 av0 = *(const f16x8*)(vb0 + i0 + ks * 16 + lh * 8);
            f16x8 av1 = *(const f16x8*)(vb1 + i0 + ks * 16 + lh * 8);
            f16x8 bp0 = *(const f16x8*)&Ps[lm * P_STRIDE + ks * 16 + lh * 8];
            f16x8 bp1 = *(const f16x8*)&Ps[(32 + lm) * P_STRIDE + ks * 16 + lh * 8];
            facc[0] = __builtin_amdgcn_mfma_f32_32x32x16_f16(av0, bp0, facc[0], 0, 0, 0);
            facc[1] = __builtin_amdgcn_mfma_f32_32x32x16_f16(av0, bp1, facc[1], 0, 0, 0);
            facc[2] = __builtin_amdgcn_mfma_f32_32x32x16_f16(av1, bp0, facc[2], 0, 0, 0);
            facc[3] = __builtin_amdgcn_mfma_f32_32x32x16_f16(av1, bp1, facc[3], 0, 0, 0);
        }
    }

    // partial F out: Fp[bq][qtr][c][p] fp32, lanes lm -> consecutive p
    float* dst = Fp + ((size_t)bq * 4 + qtr) * (CDIM * 64);
    #pragma unroll
    for (int ii = 0; ii < 2; ++ii)
        #pragma unroll
        for (int jj = 0; jj < 2; ++jj)
            #pragma unroll
            for (int r = 0; r < 16; ++r) {
                int c = w * 64 + ii * 32 + (r & 3) + 8 * (r >> 2) + 4 * lh;
                int p = jj * 32 + lm;
                dst[c * 64 + p] = facc[ii * 2 + jj][r];
            }
}

// ---------------------------------------------------------------------------
// merge_ln: grid 256 = (b<<6 | qtile), 256 thr. Sums the 4 quarter-partials
// into LDS, computes per-position mean/var over channels, writes normalized
// output. Memory-bound (~80 MB traffic).
// ---------------------------------------------------------------------------
__global__ __launch_bounds__(256, 2) void merge_ln_kernel(
    const float* __restrict__ Fp, const float* __restrict__ ln_w,
    const float* __restrict__ ln_b, float* __restrict__ out)
{
    __shared__ float Fs[256 * F_STRIDE];          // 69632 B
    __shared__ float redS[16 * 64], redQ[16 * 64];
    __shared__ float lnw_s[256], lnb_s[256];
    __shared__ float mu_s[64], rs_s[64];

    const int t  = threadIdx.x;
    const int bq = blockIdx.x;
    const int b  = bq >> 6;
    const int p0 = (bq & 63) << 6;

    lnw_s[t] = ln_w[t]; lnb_s[t] = ln_b[t];

    const int pb = (t & 15) * 4;      // 4 consecutive positions
    const int cg = t >> 4;            // 16-channel group
    const float* base = Fp + (size_t)bq * 4 * (CDIM * 64);

    f32x4 s4 = {}, q4 = {};
    #pragma unroll 4
    for (int ci = 0; ci < 16; ++ci) {
        int c = cg * 16 + ci;
        size_t off = (size_t)c * 64 + pb;
        f32x4 v = *(const f32x4*)(base + off);
        v += *(const f32x4*)(base + (size_t)(CDIM * 64) + off);
        v += *(const f32x4*)(base + (size_t)(2 * CDIM * 64) + off);
        v += *(const f32x4*)(base + (size_t)(3 * CDIM * 64) + off);
        *(f32x4*)&Fs[c * F_STRIDE + pb] = v;
        s4 += v; q4 += v * v;
    }
    #pragma unroll
    for (int k2 = 0; k2 < 4; ++k2) {
        redS[cg * 64 + pb + k2] = s4[k2];
        redQ[cg * 64 + pb + k2] = q4[k2];
    }
    __syncthreads();
    if (t < 64) {
        float ss = 0.f, qq = 0.f;
        #pragma unroll
        for (int g2 = 0; g2 < 16; ++g2) { ss += redS[g2 * 64 + t]; qq += redQ[g2 * 64 + t]; }
        float mean = ss * (1.0f / 256.0f);
        float var  = qq * (1.0f / 256.0f) - mean * mean;
        mu_s[t] = mean;
        rs_s[t] = rsqrtf(var + EPSV);
    }
    __syncthreads();
    const int p   = t & 63;
    const int cg2 = t >> 6;
    const float mu = mu_s[p], rs = rs_s[p];
    float* dst = out + (size_t)b * CDIM * NPOS + p0 + p;
    #pragma unroll 4
    for (int ci = 0; ci < 64; ++ci) {
        int c = cg2 * 64 + ci;
        dst[(size_t)c * NPOS] = (Fs[c * F_STRIDE + p] - mu) * rs * lnw_s[c] + lnb_s[c];
    }
}

// ---------------------------------------------------------------------------
extern "C" void kernel_launch(void* const* d_in, const int* in_sizes, int n_in,
                              void* d_out, int out_size, void* d_ws, size_t ws_size,
                              hipStream_t stream)
{
    const float* x1  = (const float*)d_in[0];
    const float* x2  = (const float*)d_in[1];
    const float* qw  = (const float*)d_in[2];
    const float* qb  = (const float*)d_in[3];
    const float* kw  = (const float*)d_in[4];
    const float* kb  = (const float*)d_in[5];
    const float* vw  = (const float*)d_in[6];
    const float* vb  = (const float*)d_in[7];
    const float* lnw = (const float*)d_in[8];
    const float* lnb = (const float*)d_in[9];

    const size_t tsz = (size_t)BATCH * NPOS * CDIM;
    f16* Qg  = (f16*)d_ws;
    f16* Kg  = Qg + tsz;
    f16* Vg  = Kg + tsz;
    f16* X1T = Vg + tsz;          // dead after gemm
    f16* X2T = X1T + tsz;         // dead after gemm
    f16* W16 = X2T + tsz;         // dead after gemm
    // Fp (64 MB fp32) reuses the X1T/X2T/W16 region (all dead once attn runs).
    float* Fp = (float*)X1T;      // total ws footprint: 24 MB (QKV) + 64 MB

    prep_kernel<<<2060, 256, 0, stream>>>(x1, x2, qw, kw, vw, X1T, X2T, W16);
    gemm_kernel<<<768, 256, 0, stream>>>(X1T, X2T, W16, qb, kb, vb, Qg, Kg, Vg);
    attn_kernel<<<1024, 256, 0, stream>>>(Qg, Kg, Vg, Fp);
    merge_ln_kernel<<<256, 256, 0, stream>>>(Fp, lnw, lnb, (float*)d_out);
}

// Round 2
// 310.415 us; speedup vs baseline: 1.1346x; 1.1346x over previous
//
#include <hip/hip_runtime.h>

// B=4, C=256, H=W=64 (N=4096). QKV 1x1conv -> spatial attention (softmax over
// j only => independent per-64-key-chunk softmax) -> channel LayerNorm.
// f16 MFMA 32x32x16, fp32 accumulation.
//
// R8: R6's proven LDS-staged inner loop (K prefetch regs -> LDS commit,
// V loads issued early, 3 barriers/chunk) transplanted into R7's independent
// block structure: grid 1024 = 4 blocks per (b,qtile), 256 thr each, 16
// chunks per block. P aliased into the S buffer (each softmax thread
// overwrites only the floats it itself read) -> LDS 51.2 KB -> 3 blocks/CU
// via launch_bounds(256,3). Independent blocks overlap softmax(VALU) with
// MFMA across blocks. Partial F fp32 -> merge_ln_kernel (unchanged from R7).
// prep/gemm identical.

#define CDIM 256
#define NPOS 4096
#define BATCH 4
#define EPSV 1e-5f

typedef _Float16 f16;
typedef __attribute__((ext_vector_type(8))) _Float16 f16x8;
typedef __attribute__((ext_vector_type(4))) float f32x4;
typedef __attribute__((ext_vector_type(16))) float f32x16;

#define WST       264   // f16; 528B = 33*16 -> b128-aligned rows
#define QK_STRIDE 264   // f16 K-tile rows
#define S_STRIDE  68    // f32; 272B = 17*16 (P f16 aliased in first 128B/row)
#define DQ_STRIDE 72
#define F_STRIDE  68    // merge kernel LDS stride (f32)

// MFMA 32x32x16 f16:
//   A: lane l holds A[m=l&31][k=(l>>5)*8+j]
//   B: lane l holds B[k=(l>>5)*8+j][n=l&31]
//   C/D: lane l, reg r -> col=l&31, row=(r&3)+8*(r>>2)+4*(l>>5)

static __device__ __forceinline__ f16x8 cvt8(const float* __restrict__ p) {
    float4 w0 = *(const float4*)p;
    float4 w1 = *(const float4*)(p + 4);
    f16x8 r;
    r[0] = (f16)w0.x; r[1] = (f16)w0.y; r[2] = (f16)w0.z; r[3] = (f16)w0.w;
    r[4] = (f16)w1.x; r[5] = (f16)w1.y; r[6] = (f16)w1.z; r[7] = (f16)w1.w;
    return r;
}

// ---------------------------------------------------------------------------
// prep: blocks 0..2047 transpose x1/x2 [C][N] fp32 -> [N][C] f16 (64x64 tiles);
// blocks 2048..2059 convert weights fp32 -> f16 [o][c].  (unchanged)
// ---------------------------------------------------------------------------
__global__ __launch_bounds__(256, 4) void prep_kernel(
    const float* __restrict__ x1, const float* __restrict__ x2,
    const float* __restrict__ qw, const float* __restrict__ kw,
    const float* __restrict__ vw,
    f16* __restrict__ X1T, f16* __restrict__ X2T, f16* __restrict__ W16)
{
    const int id = blockIdx.x;
    const int t  = threadIdx.x;
    if (id < 2048) {
        __shared__ f16 T[64 * 72];
        const float* xs = (id & 1) ? x2 : x1;
        f16* dst        = (id & 1) ? X2T : X1T;
        const int t2 = id >> 1;
        const int b  = t2 >> 8;
        const int rm = t2 & 255;
        const int c0 = (rm >> 6) * 64;
        const int n0 = (rm & 63) * 64;
        const float* src = xs + ((size_t)b * CDIM + c0) * NPOS + n0;
        const int rr = t >> 6, col = t & 63;
        #pragma unroll
        for (int j = 0; j < 16; ++j) {
            int row = rr + j * 4;
            T[col * 72 + row] = (f16)src[(size_t)row * NPOS + col];
        }
        __syncthreads();
        const int n = t >> 3, lc = (t & 7) * 8;
        f16* d0 = dst + ((size_t)b * NPOS + n0) * CDIM + c0;
        #pragma unroll
        for (int j = 0; j < 2; ++j) {
            int nn = n + j * 32;
            *(f16x8*)(d0 + (size_t)nn * CDIM + lc) = *(const f16x8*)&T[nn * 72 + lc];
        }
    } else {
        const int wblk = id - 2048;          // 0..11
        const int pr = wblk >> 2, h = wblk & 3;
        const float* W = (pr == 0 ? qw : pr == 1 ? kw : vw) + (size_t)h * 64 * CDIM;
        f16* D = W16 + (size_t)pr * CDIM * CDIM + (size_t)h * 64 * CDIM;
        #pragma unroll
        for (int i = 0; i < 8; ++i) {
            int g = t + i * 256;
            int row = g >> 5, col = (g & 31) * 8;
            *(f16x8*)(D + (size_t)row * CDIM + col) = cvt8(W + (size_t)row * CDIM + col);
        }
    }
}

// ---------------------------------------------------------------------------
// gemm: unchanged (proven correct). 768 blocks, weight quarters in LDS,
// split-k dual acc, LDS-assisted coalesced stores.
// ---------------------------------------------------------------------------
__global__ __launch_bounds__(256, 2) void gemm_kernel(
    const f16* __restrict__ X1T, const f16* __restrict__ X2T,
    const f16* __restrict__ W16,
    const float* __restrict__ qb, const float* __restrict__ kb,
    const float* __restrict__ vb,
    f16* __restrict__ Qg, f16* __restrict__ Kg, f16* __restrict__ Vg)
{
    __shared__ f16 Xs[64 * WST];
    __shared__ f16 Wh[64 * WST];
    __shared__ f16 Ds[64 * DQ_STRIDE];
    __shared__ float biasS[256];

    const int id = blockIdx.x;
    const int pr  = id >> 8;
    const int rem = id & 255;
    const int b   = rem >> 6;
    const int p0  = (rem & 63) << 6;
    const f16* XT = (pr == 0) ? X1T : X2T;
    const f16* Wp = W16 + (size_t)pr * CDIM * CDIM;
    const float* bias = pr == 0 ? qb : pr == 1 ? kb : vb;

    const int t = threadIdx.x, w = t >> 6, l = t & 63, lm = l & 31, lh = l >> 5;
    const int pt = w & 1, ot = w >> 1;

    biasS[t] = bias[t];
    #pragma unroll
    for (int it = 0; it < 8; ++it) {
        int p = w * 16 + it * 2 + lh;
        *(f16x8*)&Xs[p * WST + lm * 8] =
            *(const f16x8*)(XT + ((size_t)(b * NPOS + p0 + p)) * CDIM + lm * 8);
    }

    for (int q = 0; q < 4; ++q) {
        #pragma unroll
        for (int i = 0; i < 8; ++i) {
            int g = t + i * 256;
            int row = g >> 5, col = (g & 31) * 8;
            *(f16x8*)&Wh[row * WST + col] =
                *(const f16x8*)(Wp + (size_t)(q * 64 + row) * CDIM + col);
        }
        __syncthreads();

        f32x16 accA = {}, accB = {};
        #pragma unroll
        for (int ks = 0; ks < 16; ks += 2) {
            f16x8 x0 = *(const f16x8*)&Xs[(pt * 32 + lm) * WST + ks * 16 + lh * 8];
            f16x8 w0 = *(const f16x8*)&Wh[(ot * 32 + lm) * WST + ks * 16 + lh * 8];
            f16x8 x1v = *(const f16x8*)&Xs[(pt * 32 + lm) * WST + (ks + 1) * 16 + lh * 8];
            f16x8 w1 = *(const f16x8*)&Wh[(ot * 32 + lm) * WST + (ks + 1) * 16 + lh * 8];
            if (pr < 2) {
                accA = __builtin_amdgcn_mfma_f32_32x32x16_f16(x0, w0, accA, 0, 0, 0);
                accB = __builtin_amdgcn_mfma_f32_32x32x16_f16(x1v, w1, accB, 0, 0, 0);
            } else {
                accA = __builtin_amdgcn_mfma_f32_32x32x16_f16(w0, x0, accA, 0, 0, 0);
                accB = __builtin_amdgcn_mfma_f32_32x32x16_f16(w1, x1v, accB, 0, 0, 0);
            }
        }

        if (pr < 2) {
            int o_l = ot * 32 + lm;
            float bv = biasS[q * 64 + o_l];
            #pragma unroll
            for (int r = 0; r < 16; ++r) {
                int p_l = pt * 32 + (r & 3) + 8 * (r >> 2) + 4 * lh;
                Ds[p_l * DQ_STRIDE + o_l] = (f16)(accA[r] + accB[r] + bv);
            }
        } else {
            #pragma unroll
            for (int r = 0; r < 16; ++r) {
                int o_l = ot * 32 + (r & 3) + 8 * (r >> 2) + 4 * lh;
                Ds[o_l * DQ_STRIDE + pt * 32 + lm] =
                    (f16)(accA[r] + accB[r] + biasS[q * 64 + o_l]);
            }
        }
        __syncthreads();

        #pragma unroll
        for (int j = 0; j < 2; ++j) {
            int row = (t >> 3) + j * 32;
            int cc  = (t & 7) * 8;
            f16x8 vdat = *(const f16x8*)&Ds[row * DQ_STRIDE + cc];
            if (pr < 2) {
                f16* Out = (pr == 0) ? Qg : Kg;
                *(f16x8*)(Out + ((size_t)(b * NPOS + p0 + row)) * CDIM + q * 64 + cc) = vdat;
            } else {
                *(f16x8*)(Vg + ((size_t)(b * CDIM + q * 64 + row)) * NPOS + p0 + cc) = vdat;
            }
        }
        __syncthreads();
    }
}

// ---------------------------------------------------------------------------
// attn: grid 1024 = ((b<<6 | qtile)<<2 | quarter), 256 thr = 4 waves.
// Each block: 16 key-chunks, K prefetched to regs then committed to LDS
// (R6's proven fast path), V fragment loads issued behind the S phase,
// P f16 aliased into the first 128B of each S row. 3 barriers/chunk.
// LDS 51.2 KB -> 3 blocks/CU. Emits partial F fp32 [bq][qtr][256c][64p].
// ---------------------------------------------------------------------------
__global__ __launch_bounds__(256, 3) void attn_kernel(
    const f16* __restrict__ Qg, const f16* __restrict__ Kg, const f16* __restrict__ Vg,
    float* __restrict__ Fp)
{
    __shared__ f16   Ks[64 * QK_STRIDE];  // 33792 B
    __shared__ float Ss[64 * S_STRIDE];   // 17408 B (P f16 aliased per-row)

    const int t   = threadIdx.x;
    const int qtr = blockIdx.x & 3;
    const int bq  = blockIdx.x >> 2;
    const int b   = bq >> 6;
    const int p0  = (bq & 63) << 6;
    const int w   = t >> 6;          // 0..3
    const int l   = t & 63;
    const int lm  = l & 31;
    const int lh  = l >> 5;
    const int spt = w & 1;           // wave's S tile: query-tile spt, key-tile skt
    const int skt = w >> 1;

    // Q fragments for this wave's query-tile (registers, all chunks)
    f16x8 qf[16];
    {
        const f16* qptr = Qg + (size_t)(b * NPOS + p0 + spt * 32 + lm) * CDIM + lh * 8;
        #pragma unroll
        for (int ks = 0; ks < 16; ++ks) qf[ks] = *(const f16x8*)(qptr + ks * 16);
    }

    // K prefetch registers: this block's chunk stream = qtr*16 .. qtr*16+15
    const int kr = t >> 5, koff = (t & 31) * 8;
    f16x8 kreg[8];
    auto issue_k = [&](int ch) {
        const int i0 = ch * 64;
        #pragma unroll
        for (int r = 0; r < 8; ++r)
            kreg[r] = *(const f16x8*)(Kg + (size_t)(b * NPOS + i0 + r * 8 + kr) * CDIM + koff);
    };
    issue_k(qtr * 16);

    // V fragment bases: wave's c-strip = w*64 + {0,32}
    const f16* vb0 = Vg + (size_t)(b * CDIM + w * 64 + lm) * NPOS;
    const f16* vb1 = Vg + (size_t)(b * CDIM + w * 64 + 32 + lm) * NPOS;

    f16* Pal = (f16*)&Ss[0];          // P alias: row r at f16 offset r*136

    f32x16 facc[4] = {};      // per-wave F acc: [i=c-tile(2)][j=p-tile(2)]

    for (int it = 0; it < 16; ++it) {
        const int i0 = (qtr * 16 + it) * 64;

        // commit prefetched K to LDS
        #pragma unroll
        for (int r = 0; r < 8; ++r)
            *(f16x8*)&Ks[(r * 8 + kr) * QK_STRIDE + koff] = kreg[r];
        __syncthreads();   // A: Ks ready; prev iter's P reads done (S rows free)

        // issue this chunk's V fragment loads (hidden behind S-phase)
        f16x8 vf0[4], vf1[4];
        #pragma unroll
        for (int ks = 0; ks < 4; ++ks) {
            vf0[ks] = *(const f16x8*)(vb0 + i0 + ks * 16 + lh * 8);
            vf1[ks] = *(const f16x8*)(vb1 + i0 + ks * 16 + lh * 8);
        }

        // S = Q K^T
        f32x16 sacc = {};
        #pragma unroll
        for (int ks = 0; ks < 16; ++ks) {
            f16x8 bb = *(const f16x8*)&Ks[(skt * 32 + lm) * QK_STRIDE + ks * 16 + lh * 8];
            sacc = __builtin_amdgcn_mfma_f32_32x32x16_f16(qf[ks], bb, sacc, 0, 0, 0);
        }
        #pragma unroll
        for (int r = 0; r < 16; ++r) {
            int row = (r & 3) + 8 * (r >> 2) + 4 * lh;
            Ss[(spt * 32 + row) * S_STRIDE + skt * 32 + lm] = sacc[r];
        }
        __syncthreads();   // B: Ss ready

        // softmax per row: 4 threads/row x 16 elems; P written in place
        {
            const int r  = t >> 2;
            const int sg = (t & 3) * 16;
            const float* srow = &Ss[r * S_STRIDE + sg];
            float v[16];
            f32x4 a0 = *(const f32x4*)(srow);
            f32x4 a1 = *(const f32x4*)(srow + 4);
            f32x4 a2 = *(const f32x4*)(srow + 8);
            f32x4 a3 = *(const f32x4*)(srow + 12);
            v[0]=a0[0]; v[1]=a0[1]; v[2]=a0[2]; v[3]=a0[3];
            v[4]=a1[0]; v[5]=a1[1]; v[6]=a1[2]; v[7]=a1[3];
            v[8]=a2[0]; v[9]=a2[1]; v[10]=a2[2]; v[11]=a2[3];
            v[12]=a3[0]; v[13]=a3[1]; v[14]=a3[2]; v[15]=a3[3];
            float m = v[0];
            #pragma unroll
            for (int i = 1; i < 16; ++i) m = fmaxf(m, v[i]);
            m = fmaxf(m, __shfl_xor(m, 1));
            m = fmaxf(m, __shfl_xor(m, 2));
            float s = 0.f;
            #pragma unroll
            for (int i = 0; i < 16; ++i) { float e = __expf(v[i] - m); v[i] = e; s += e; }
            s += __shfl_xor(s, 1);
            s += __shfl_xor(s, 2);
            float inv = __builtin_amdgcn_rcpf(s);
            f16x8 h0, h1;
            #pragma unroll
            for (int i = 0; i < 8; ++i) { h0[i] = (f16)(v[i] * inv); h1[i] = (f16)(v[i + 8] * inv); }
            // in-place: this thread only overwrites floats it itself read
            *(f16x8*)&Pal[r * 136 + sg]     = h0;
            *(f16x8*)&Pal[r * 136 + sg + 8] = h1;
        }
        __syncthreads();   // C: P ready

        if (it < 15) issue_k(qtr * 16 + it + 1);   // hidden behind PV

        // F += V * P^T
        #pragma unroll
        for (int ks = 0; ks < 4; ++ks) {
            f16x8 bp0 = *(const f16x8*)&Pal[lm * 136 + ks * 16 + lh * 8];
            f16x8 bp1 = *(const f16x8*)&Pal[(32 + lm) * 136 + ks * 16 + lh * 8];
            facc[0] = __builtin_amdgcn_mfma_f32_32x32x16_f16(vf0[ks], bp0, facc[0], 0, 0, 0);
            facc[1] = __builtin_amdgcn_mfma_f32_32x32x16_f16(vf0[ks], bp1, facc[1], 0, 0, 0);
            facc[2] = __builtin_amdgcn_mfma_f32_32x32x16_f16(vf1[ks], bp0, facc[2], 0, 0, 0);
            facc[3] = __builtin_amdgcn_mfma_f32_32x32x16_f16(vf1[ks], bp1, facc[3], 0, 0, 0);
        }
    }

    // partial F out: Fp[bq][qtr][c][p] fp32, lanes lm -> consecutive p
    float* dst = Fp + ((size_t)bq * 4 + qtr) * (CDIM * 64);
    #pragma unroll
    for (int ii = 0; ii < 2; ++ii)
        #pragma unroll
        for (int jj = 0; jj < 2; ++jj)
            #pragma unroll
            for (int r = 0; r < 16; ++r) {
                int c = w * 64 + ii * 32 + (r & 3) + 8 * (r >> 2) + 4 * lh;
                int p = jj * 32 + lm;
                dst[c * 64 + p] = facc[ii * 2 + jj][r];
            }
}

// ---------------------------------------------------------------------------
// merge_ln: grid 256 = (b<<6 | qtile), 256 thr. Sums the 4 quarter-partials
// into LDS, computes per-position mean/var over channels, writes normalized
// output. Memory-bound (~80 MB traffic). (unchanged from R7, proven correct)
// ---------------------------------------------------------------------------
__global__ __launch_bounds__(256, 2) void merge_ln_kernel(
    const float* __restrict__ Fp, const float* __restrict__ ln_w,
    const float* __restrict__ ln_b, float* __restrict__ out)
{
    __shared__ float Fs[256 * F_STRIDE];          // 69632 B
    __shared__ float redS[16 * 64], redQ[16 * 64];
    __shared__ float lnw_s[256], lnb_s[256];
    __shared__ float mu_s[64], rs_s[64];

    const int t  = threadIdx.x;
    const int bq = blockIdx.x;
    const int b  = bq >> 6;
    const int p0 = (bq & 63) << 6;

    lnw_s[t] = ln_w[t]; lnb_s[t] = ln_b[t];

    const int pb = (t & 15) * 4;      // 4 consecutive positions
    const int cg = t >> 4;            // 16-channel group
    const float* base = Fp + (size_t)bq * 4 * (CDIM * 64);

    f32x4 s4 = {}, q4 = {};
    #pragma unroll 4
    for (int ci = 0; ci < 16; ++ci) {
        int c = cg * 16 + ci;
        size_t off = (size_t)c * 64 + pb;
        f32x4 v = *(const f32x4*)(base + off);
        v += *(const f32x4*)(base + (size_t)(CDIM * 64) + off);
        v += *(const f32x4*)(base + (size_t)(2 * CDIM * 64) + off);
        v += *(const f32x4*)(base + (size_t)(3 * CDIM * 64) + off);
        *(f32x4*)&Fs[c * F_STRIDE + pb] = v;
        s4 += v; q4 += v * v;
    }
    #pragma unroll
    for (int k2 = 0; k2 < 4; ++k2) {
        redS[cg * 64 + pb + k2] = s4[k2];
        redQ[cg * 64 + pb + k2] = q4[k2];
    }
    __syncthreads();
    if (t < 64) {
        float ss = 0.f, qq = 0.f;
        #pragma unroll
        for (int g2 = 0; g2 < 16; ++g2) { ss += redS[g2 * 64 + t]; qq += redQ[g2 * 64 + t]; }
        float mean = ss * (1.0f / 256.0f);
        float var  = qq * (1.0f / 256.0f) - mean * mean;
        mu_s[t] = mean;
        rs_s[t] = rsqrtf(var + EPSV);
    }
    __syncthreads();
    const int p   = t & 63;
    const int cg2 = t >> 6;
    const float mu = mu_s[p], rs = rs_s[p];
    float* dst = out + (size_t)b * CDIM * NPOS + p0 + p;
    #pragma unroll 4
    for (int ci = 0; ci < 64; ++ci) {
        int c = cg2 * 64 + ci;
        dst[(size_t)c * NPOS] = (Fs[c * F_STRIDE + p] - mu) * rs * lnw_s[c] + lnb_s[c];
    }
}

// ---------------------------------------------------------------------------
extern "C" void kernel_launch(void* const* d_in, const int* in_sizes, int n_in,
                              void* d_out, int out_size, void* d_ws, size_t ws_size,
                              hipStream_t stream)
{
    const float* x1  = (const float*)d_in[0];
    const float* x2  = (const float*)d_in[1];
    const float* qw  = (const float*)d_in[2];
    const float* qb  = (const float*)d_in[3];
    const float* kw  = (const float*)d_in[4];
    const float* kb  = (const float*)d_in[5];
    const float* vw  = (const float*)d_in[6];
    const float* vb  = (const float*)d_in[7];
    const float* lnw = (const float*)d_in[8];
    const float* lnb = (const float*)d_in[9];

    const size_t tsz = (size_t)BATCH * NPOS * CDIM;
    f16* Qg  = (f16*)d_ws;
    f16* Kg  = Qg + tsz;
    f16* Vg  = Kg + tsz;
    f16* X1T = Vg + tsz;          // dead after gemm
    f16* X2T = X1T + tsz;         // dead after gemm
    f16* W16 = X2T + tsz;         // dead after gemm
    // Fp (64 MB fp32) reuses the X1T/X2T/W16 region (all dead once attn runs).
    float* Fp = (float*)X1T;      // total ws footprint: 24 MB (QKV) + 64 MB

    prep_kernel<<<2060, 256, 0, stream>>>(x1, x2, qw, kw, vw, X1T, X2T, W16);
    gemm_kernel<<<768, 256, 0, stream>>>(X1T, X2T, W16, qb, kb, vb, Qg, Kg, Vg);
    attn_kernel<<<1024, 256, 0, stream>>>(Qg, Kg, Vg, Fp);
    merge_ln_kernel<<<256, 256, 0, stream>>>(Fp, lnw, lnb, (float*)d_out);
}

// Round 3
// 222.125 us; speedup vs baseline: 1.5855x; 1.3975x over previous
//
#include <hip/hip_runtime.h>

// B=4, C=256, H=W=64 (N=4096). QKV 1x1conv -> spatial attention (softmax over
// j only => independent per-64-key-chunk softmax) -> channel LayerNorm.
// f16 MFMA 32x32x16, fp32 accumulation.
//
// R9: fix R7/R8's register strangulation. launch_bounds(256,3) capped the
// unified VGPR+AGPR file at ~170/wave vs ~230 live state -> scratch spills on
// the MFMA critical path (WRITE_SIZE 113MB vs 64MB algorithmic = smoking gun).
// Now: launch_bounds(256,2) (256 regs/wave, no spill), grid 512 = 2 halves
// per (b,qtile) x 32 chunks, ALL blocks co-resident in one pass (2 blocks/CU,
// 2 waves/SIMD from different blocks -> softmax||MFMA cross-block overlap).
// Bijective chunked XCD swizzle: each XCD's 64 blocks = one (b,half) group,
// working set K-half 1MB + V-half 1MB + Q 2MB = 4MB = one L2. Fp partials
// 4->2 (32MB). prep/gemm identical (proven).

#define CDIM 256
#define NPOS 4096
#define BATCH 4
#define EPSV 1e-5f

typedef _Float16 f16;
typedef __attribute__((ext_vector_type(8))) _Float16 f16x8;
typedef __attribute__((ext_vector_type(4))) float f32x4;
typedef __attribute__((ext_vector_type(16))) float f32x16;

#define WST       264   // f16; 528B = 33*16 -> b128-aligned rows
#define QK_STRIDE 264   // f16 K-tile rows
#define S_STRIDE  68    // f32; 272B = 17*16 (P f16 aliased in first 128B/row)
#define DQ_STRIDE 72
#define F_STRIDE  68    // merge kernel LDS stride (f32)

// MFMA 32x32x16 f16:
//   A: lane l holds A[m=l&31][k=(l>>5)*8+j]
//   B: lane l holds B[k=(l>>5)*8+j][n=l&31]
//   C/D: lane l, reg r -> col=l&31, row=(r&3)+8*(r>>2)+4*(l>>5)

static __device__ __forceinline__ f16x8 cvt8(const float* __restrict__ p) {
    float4 w0 = *(const float4*)p;
    float4 w1 = *(const float4*)(p + 4);
    f16x8 r;
    r[0] = (f16)w0.x; r[1] = (f16)w0.y; r[2] = (f16)w0.z; r[3] = (f16)w0.w;
    r[4] = (f16)w1.x; r[5] = (f16)w1.y; r[6] = (f16)w1.z; r[7] = (f16)w1.w;
    return r;
}

// ---------------------------------------------------------------------------
// prep: blocks 0..2047 transpose x1/x2 [C][N] fp32 -> [N][C] f16 (64x64 tiles);
// blocks 2048..2059 convert weights fp32 -> f16 [o][c].  (unchanged)
// ---------------------------------------------------------------------------
__global__ __launch_bounds__(256, 4) void prep_kernel(
    const float* __restrict__ x1, const float* __restrict__ x2,
    const float* __restrict__ qw, const float* __restrict__ kw,
    const float* __restrict__ vw,
    f16* __restrict__ X1T, f16* __restrict__ X2T, f16* __restrict__ W16)
{
    const int id = blockIdx.x;
    const int t  = threadIdx.x;
    if (id < 2048) {
        __shared__ f16 T[64 * 72];
        const float* xs = (id & 1) ? x2 : x1;
        f16* dst        = (id & 1) ? X2T : X1T;
        const int t2 = id >> 1;
        const int b  = t2 >> 8;
        const int rm = t2 & 255;
        const int c0 = (rm >> 6) * 64;
        const int n0 = (rm & 63) * 64;
        const float* src = xs + ((size_t)b * CDIM + c0) * NPOS + n0;
        const int rr = t >> 6, col = t & 63;
        #pragma unroll
        for (int j = 0; j < 16; ++j) {
            int row = rr + j * 4;
            T[col * 72 + row] = (f16)src[(size_t)row * NPOS + col];
        }
        __syncthreads();
        const int n = t >> 3, lc = (t & 7) * 8;
        f16* d0 = dst + ((size_t)b * NPOS + n0) * CDIM + c0;
        #pragma unroll
        for (int j = 0; j < 2; ++j) {
            int nn = n + j * 32;
            *(f16x8*)(d0 + (size_t)nn * CDIM + lc) = *(const f16x8*)&T[nn * 72 + lc];
        }
    } else {
        const int wblk = id - 2048;          // 0..11
        const int pr = wblk >> 2, h = wblk & 3;
        const float* W = (pr == 0 ? qw : pr == 1 ? kw : vw) + (size_t)h * 64 * CDIM;
        f16* D = W16 + (size_t)pr * CDIM * CDIM + (size_t)h * 64 * CDIM;
        #pragma unroll
        for (int i = 0; i < 8; ++i) {
            int g = t + i * 256;
            int row = g >> 5, col = (g & 31) * 8;
            *(f16x8*)(D + (size_t)row * CDIM + col) = cvt8(W + (size_t)row * CDIM + col);
        }
    }
}

// ---------------------------------------------------------------------------
// gemm: unchanged (proven correct). 768 blocks, weight quarters in LDS,
// split-k dual acc, LDS-assisted coalesced stores.
// ---------------------------------------------------------------------------
__global__ __launch_bounds__(256, 2) void gemm_kernel(
    const f16* __restrict__ X1T, const f16* __restrict__ X2T,
    const f16* __restrict__ W16,
    const float* __restrict__ qb, const float* __restrict__ kb,
    const float* __restrict__ vb,
    f16* __restrict__ Qg, f16* __restrict__ Kg, f16* __restrict__ Vg)
{
    __shared__ f16 Xs[64 * WST];
    __shared__ f16 Wh[64 * WST];
    __shared__ f16 Ds[64 * DQ_STRIDE];
    __shared__ float biasS[256];

    const int id = blockIdx.x;
    const int pr  = id >> 8;
    const int rem = id & 255;
    const int b   = rem >> 6;
    const int p0  = (rem & 63) << 6;
    const f16* XT = (pr == 0) ? X1T : X2T;
    const f16* Wp = W16 + (size_t)pr * CDIM * CDIM;
    const float* bias = pr == 0 ? qb : pr == 1 ? kb : vb;

    const int t = threadIdx.x, w = t >> 6, l = t & 63, lm = l & 31, lh = l >> 5;
    const int pt = w & 1, ot = w >> 1;

    biasS[t] = bias[t];
    #pragma unroll
    for (int it = 0; it < 8; ++it) {
        int p = w * 16 + it * 2 + lh;
        *(f16x8*)&Xs[p * WST + lm * 8] =
            *(const f16x8*)(XT + ((size_t)(b * NPOS + p0 + p)) * CDIM + lm * 8);
    }

    for (int q = 0; q < 4; ++q) {
        #pragma unroll
        for (int i = 0; i < 8; ++i) {
            int g = t + i * 256;
            int row = g >> 5, col = (g & 31) * 8;
            *(f16x8*)&Wh[row * WST + col] =
                *(const f16x8*)(Wp + (size_t)(q * 64 + row) * CDIM + col);
        }
        __syncthreads();

        f32x16 accA = {}, accB = {};
        #pragma unroll
        for (int ks = 0; ks < 16; ks += 2) {
            f16x8 x0 = *(const f16x8*)&Xs[(pt * 32 + lm) * WST + ks * 16 + lh * 8];
            f16x8 w0 = *(const f16x8*)&Wh[(ot * 32 + lm) * WST + ks * 16 + lh * 8];
            f16x8 x1v = *(const f16x8*)&Xs[(pt * 32 + lm) * WST + (ks + 1) * 16 + lh * 8];
            f16x8 w1 = *(const f16x8*)&Wh[(ot * 32 + lm) * WST + (ks + 1) * 16 + lh * 8];
            if (pr < 2) {
                accA = __builtin_amdgcn_mfma_f32_32x32x16_f16(x0, w0, accA, 0, 0, 0);
                accB = __builtin_amdgcn_mfma_f32_32x32x16_f16(x1v, w1, accB, 0, 0, 0);
            } else {
                accA = __builtin_amdgcn_mfma_f32_32x32x16_f16(w0, x0, accA, 0, 0, 0);
                accB = __builtin_amdgcn_mfma_f32_32x32x16_f16(w1, x1v, accB, 0, 0, 0);
            }
        }

        if (pr < 2) {
            int o_l = ot * 32 + lm;
            float bv = biasS[q * 64 + o_l];
            #pragma unroll
            for (int r = 0; r < 16; ++r) {
                int p_l = pt * 32 + (r & 3) + 8 * (r >> 2) + 4 * lh;
                Ds[p_l * DQ_STRIDE + o_l] = (f16)(accA[r] + accB[r] + bv);
            }
        } else {
            #pragma unroll
            for (int r = 0; r < 16; ++r) {
                int o_l = ot * 32 + (r & 3) + 8 * (r >> 2) + 4 * lh;
                Ds[o_l * DQ_STRIDE + pt * 32 + lm] =
                    (f16)(accA[r] + accB[r] + biasS[q * 64 + o_l]);
            }
        }
        __syncthreads();

        #pragma unroll
        for (int j = 0; j < 2; ++j) {
            int row = (t >> 3) + j * 32;
            int cc  = (t & 7) * 8;
            f16x8 vdat = *(const f16x8*)&Ds[row * DQ_STRIDE + cc];
            if (pr < 2) {
                f16* Out = (pr == 0) ? Qg : Kg;
                *(f16x8*)(Out + ((size_t)(b * NPOS + p0 + row)) * CDIM + q * 64 + cc) = vdat;
            } else {
                *(f16x8*)(Vg + ((size_t)(b * CDIM + q * 64 + row)) * NPOS + p0 + cc) = vdat;
            }
        }
        __syncthreads();
    }
}

// ---------------------------------------------------------------------------
// attn: grid 512, 256 thr = 4 waves, launch_bounds(256,2) -> no spills,
// 2 blocks/CU, all blocks co-resident (one pass). Logical id via bijective
// chunked XCD swizzle: L = (hw&7)*64 + (hw>>3); decode (b, half, qtile) so
// each XCD's 64 blocks share one (b,half) K/V stream (4MB = one L2).
// Per block: 32 key-chunks, K prefetch regs -> LDS commit, V loads behind
// S phase, P f16 aliased into S rows, 3 barriers/chunk. LDS 51.2 KB.
// Emits partial F fp32 [bq][half][256c][64p].
// ---------------------------------------------------------------------------
__global__ __launch_bounds__(256, 2) void attn_kernel(
    const f16* __restrict__ Qg, const f16* __restrict__ Kg, const f16* __restrict__ Vg,
    float* __restrict__ Fp)
{
    __shared__ f16   Ks[64 * QK_STRIDE];  // 33792 B
    __shared__ float Ss[64 * S_STRIDE];   // 17408 B (P f16 aliased per-row)

    const int t    = threadIdx.x;
    const int L    = (int)((blockIdx.x & 7) * 64 + (blockIdx.x >> 3)); // XCD swizzle
    const int grp  = L >> 6;         // 0..7 = (b<<1 | half)
    const int b    = grp >> 1;
    const int half = grp & 1;
    const int qt   = L & 63;
    const int p0   = qt << 6;
    const int bq   = b * 64 + qt;
    const int w    = t >> 6;         // 0..3
    const int l    = t & 63;
    const int lm   = l & 31;
    const int lh   = l >> 5;
    const int spt  = w & 1;          // wave's S tile: query-tile spt, key-tile skt
    const int skt  = w >> 1;

    // Q fragments for this wave's query-tile (registers, all chunks)
    f16x8 qf[16];
    {
        const f16* qptr = Qg + (size_t)(b * NPOS + p0 + spt * 32 + lm) * CDIM + lh * 8;
        #pragma unroll
        for (int ks = 0; ks < 16; ++ks) qf[ks] = *(const f16x8*)(qptr + ks * 16);
    }

    // K prefetch registers: this block's chunk stream = half*32 .. half*32+31
    const int kr = t >> 5, koff = (t & 31) * 8;
    f16x8 kreg[8];
    auto issue_k = [&](int ch) {
        const int i0 = ch * 64;
        #pragma unroll
        for (int r = 0; r < 8; ++r)
            kreg[r] = *(const f16x8*)(Kg + (size_t)(b * NPOS + i0 + r * 8 + kr) * CDIM + koff);
    };
    issue_k(half * 32);

    // V fragment bases: wave's c-strip = w*64 + {0,32}
    const f16* vb0 = Vg + (size_t)(b * CDIM + w * 64 + lm) * NPOS;
    const f16* vb1 = Vg + (size_t)(b * CDIM + w * 64 + 32 + lm) * NPOS;

    f16* Pal = (f16*)&Ss[0];          // P alias: row r at f16 offset r*136

    f32x16 facc[4] = {};      // per-wave F acc: [i=c-tile(2)][j=p-tile(2)]

    for (int it = 0; it < 32; ++it) {
        const int i0 = (half * 32 + it) * 64;

        // commit prefetched K to LDS
        #pragma unroll
        for (int r = 0; r < 8; ++r)
            *(f16x8*)&Ks[(r * 8 + kr) * QK_STRIDE + koff] = kreg[r];
        __syncthreads();   // A: Ks ready; prev iter's P reads done (S rows free)

        // issue this chunk's V fragment loads (hidden behind S-phase)
        f16x8 vf0[4], vf1[4];
        #pragma unroll
        for (int ks = 0; ks < 4; ++ks) {
            vf0[ks] = *(const f16x8*)(vb0 + i0 + ks * 16 + lh * 8);
            vf1[ks] = *(const f16x8*)(vb1 + i0 + ks * 16 + lh * 8);
        }

        // S = Q K^T
        f32x16 sacc = {};
        #pragma unroll
        for (int ks = 0; ks < 16; ++ks) {
            f16x8 bb = *(const f16x8*)&Ks[(skt * 32 + lm) * QK_STRIDE + ks * 16 + lh * 8];
            sacc = __builtin_amdgcn_mfma_f32_32x32x16_f16(qf[ks], bb, sacc, 0, 0, 0);
        }
        #pragma unroll
        for (int r = 0; r < 16; ++r) {
            int row = (r & 3) + 8 * (r >> 2) + 4 * lh;
            Ss[(spt * 32 + row) * S_STRIDE + skt * 32 + lm] = sacc[r];
        }
        __syncthreads();   // B: Ss ready

        // softmax per row: 4 threads/row x 16 elems; P written in place
        {
            const int r  = t >> 2;
            const int sg = (t & 3) * 16;
            const float* srow = &Ss[r * S_STRIDE + sg];
            float v[16];
            f32x4 a0 = *(const f32x4*)(srow);
            f32x4 a1 = *(const f32x4*)(srow + 4);
            f32x4 a2 = *(const f32x4*)(srow + 8);
            f32x4 a3 = *(const f32x4*)(srow + 12);
            v[0]=a0[0]; v[1]=a0[1]; v[2]=a0[2]; v[3]=a0[3];
            v[4]=a1[0]; v[5]=a1[1]; v[6]=a1[2]; v[7]=a1[3];
            v[8]=a2[0]; v[9]=a2[1]; v[10]=a2[2]; v[11]=a2[3];
            v[12]=a3[0]; v[13]=a3[1]; v[14]=a3[2]; v[15]=a3[3];
            float m = v[0];
            #pragma unroll
            for (int i = 1; i < 16; ++i) m = fmaxf(m, v[i]);
            m = fmaxf(m, __shfl_xor(m, 1));
            m = fmaxf(m, __shfl_xor(m, 2));
            float s = 0.f;
            #pragma unroll
            for (int i = 0; i < 16; ++i) { float e = __expf(v[i] - m); v[i] = e; s += e; }
            s += __shfl_xor(s, 1);
            s += __shfl_xor(s, 2);
            float inv = __builtin_amdgcn_rcpf(s);
            f16x8 h0, h1;
            #pragma unroll
            for (int i = 0; i < 8; ++i) { h0[i] = (f16)(v[i] * inv); h1[i] = (f16)(v[i + 8] * inv); }
            // in-place: this thread only overwrites floats it itself read
            *(f16x8*)&Pal[r * 136 + sg]     = h0;
            *(f16x8*)&Pal[r * 136 + sg + 8] = h1;
        }
        __syncthreads();   // C: P ready

        if (it < 31) issue_k(half * 32 + it + 1);   // hidden behind PV

        // F += V * P^T
        #pragma unroll
        for (int ks = 0; ks < 4; ++ks) {
            f16x8 bp0 = *(const f16x8*)&Pal[lm * 136 + ks * 16 + lh * 8];
            f16x8 bp1 = *(const f16x8*)&Pal[(32 + lm) * 136 + ks * 16 + lh * 8];
            facc[0] = __builtin_amdgcn_mfma_f32_32x32x16_f16(vf0[ks], bp0, facc[0], 0, 0, 0);
            facc[1] = __builtin_amdgcn_mfma_f32_32x32x16_f16(vf0[ks], bp1, facc[1], 0, 0, 0);
            facc[2] = __builtin_amdgcn_mfma_f32_32x32x16_f16(vf1[ks], bp0, facc[2], 0, 0, 0);
            facc[3] = __builtin_amdgcn_mfma_f32_32x32x16_f16(vf1[ks], bp1, facc[3], 0, 0, 0);
        }
    }

    // partial F out: Fp[bq][half][c][p] fp32, lanes lm -> consecutive p
    float* dst = Fp + ((size_t)bq * 2 + half) * (CDIM * 64);
    #pragma unroll
    for (int ii = 0; ii < 2; ++ii)
        #pragma unroll
        for (int jj = 0; jj < 2; ++jj)
            #pragma unroll
            for (int r = 0; r < 16; ++r) {
                int c = w * 64 + ii * 32 + (r & 3) + 8 * (r >> 2) + 4 * lh;
                int p = jj * 32 + lm;
                dst[c * 64 + p] = facc[ii * 2 + jj][r];
            }
}

// ---------------------------------------------------------------------------
// merge_ln: grid 256 = (b<<6 | qtile), 256 thr. Sums the 2 half-partials
// into LDS, computes per-position mean/var over channels, writes normalized
// output. Memory-bound (~48 MB traffic).
// ---------------------------------------------------------------------------
__global__ __launch_bounds__(256, 2) void merge_ln_kernel(
    const float* __restrict__ Fp, const float* __restrict__ ln_w,
    const float* __restrict__ ln_b, float* __restrict__ out)
{
    __shared__ float Fs[256 * F_STRIDE];          // 69632 B
    __shared__ float redS[16 * 64], redQ[16 * 64];
    __shared__ float lnw_s[256], lnb_s[256];
    __shared__ float mu_s[64], rs_s[64];

    const int t  = threadIdx.x;
    const int bq = blockIdx.x;
    const int b  = bq >> 6;
    const int p0 = (bq & 63) << 6;

    lnw_s[t] = ln_w[t]; lnb_s[t] = ln_b[t];

    const int pb = (t & 15) * 4;      // 4 consecutive positions
    const int cg = t >> 4;            // 16-channel group
    const float* base = Fp + (size_t)bq * 2 * (CDIM * 64);

    f32x4 s4 = {}, q4 = {};
    #pragma unroll 4
    for (int ci = 0; ci < 16; ++ci) {
        int c = cg * 16 + ci;
        size_t off = (size_t)c * 64 + pb;
        f32x4 v = *(const f32x4*)(base + off);
        v += *(const f32x4*)(base + (size_t)(CDIM * 64) + off);
        *(f32x4*)&Fs[c * F_STRIDE + pb] = v;
        s4 += v; q4 += v * v;
    }
    #pragma unroll
    for (int k2 = 0; k2 < 4; ++k2) {
        redS[cg * 64 + pb + k2] = s4[k2];
        redQ[cg * 64 + pb + k2] = q4[k2];
    }
    __syncthreads();
    if (t < 64) {
        float ss = 0.f, qq = 0.f;
        #pragma unroll
        for (int g2 = 0; g2 < 16; ++g2) { ss += redS[g2 * 64 + t]; qq += redQ[g2 * 64 + t]; }
        float mean = ss * (1.0f / 256.0f);
        float var  = qq * (1.0f / 256.0f) - mean * mean;
        mu_s[t] = mean;
        rs_s[t] = rsqrtf(var + EPSV);
    }
    __syncthreads();
    const int p   = t & 63;
    const int cg2 = t >> 6;
    const float mu = mu_s[p], rs = rs_s[p];
    float* dst = out + (size_t)b * CDIM * NPOS + p0 + p;
    #pragma unroll 4
    for (int ci = 0; ci < 64; ++ci) {
        int c = cg2 * 64 + ci;
        dst[(size_t)c * NPOS] = (Fs[c * F_STRIDE + p] - mu) * rs * lnw_s[c] + lnb_s[c];
    }
}

// ---------------------------------------------------------------------------
extern "C" void kernel_launch(void* const* d_in, const int* in_sizes, int n_in,
                              void* d_out, int out_size, void* d_ws, size_t ws_size,
                              hipStream_t stream)
{
    const float* x1  = (const float*)d_in[0];
    const float* x2  = (const float*)d_in[1];
    const float* qw  = (const float*)d_in[2];
    const float* qb  = (const float*)d_in[3];
    const float* kw  = (const float*)d_in[4];
    const float* kb  = (const float*)d_in[5];
    const float* vw  = (const float*)d_in[6];
    const float* vb  = (const float*)d_in[7];
    const float* lnw = (const float*)d_in[8];
    const float* lnb = (const float*)d_in[9];

    const size_t tsz = (size_t)BATCH * NPOS * CDIM;
    f16* Qg  = (f16*)d_ws;
    f16* Kg  = Qg + tsz;
    f16* Vg  = Kg + tsz;
    f16* X1T = Vg + tsz;          // dead after gemm
    f16* X2T = X1T + tsz;         // dead after gemm
    f16* W16 = X2T + tsz;         // dead after gemm
    // Fp (32 MB fp32) reuses the X1T/X2T/W16 region (all dead once attn runs).
    float* Fp = (float*)X1T;      // total ws footprint: 24 MB (QKV) + 32 MB

    prep_kernel<<<2060, 256, 0, stream>>>(x1, x2, qw, kw, vw, X1T, X2T, W16);
    gemm_kernel<<<768, 256, 0, stream>>>(X1T, X2T, W16, qb, kb, vb, Qg, Kg, Vg);
    attn_kernel<<<512, 256, 0, stream>>>(Qg, Kg, Vg, Fp);
    merge_ln_kernel<<<256, 256, 0, stream>>>(Fp, lnw, lnb, (float*)d_out);
}

// Round 4
// 217.845 us; speedup vs baseline: 1.6167x; 1.0196x over previous
//
#include <hip/hip_runtime.h>

// B=4, C=256, H=W=64 (N=4096). QKV 1x1conv -> spatial attention (softmax over
// j only => independent per-64-key-chunk softmax) -> channel LayerNorm.
// f16 MFMA 32x32x16, fp32 accumulation.
//
// R10: R9 structure (grid 512, 2 blocks/CU co-resident, XCD swizzle, no
// spills) + barrier-drain removal. __syncthreads() emits s_waitcnt vmcnt(0)
// before s_barrier (HIP structural), draining the uncoalesced V loads and K
// prefetch at every barrier -> ~7K stall cycles/chunk. Barriers A/B/C only
// guard LDS, so replace with asm {s_waitcnt lgkmcnt(0); s_barrier} (memory
// clobber): global loads stay in flight, consumed via register-dep counted
// vmcnt (T3/T4 mechanism). Also: K prefetch moved to full-chunk window,
// QK^T accumulator split into 2 chains (dep depth 16->8), setprio(1) around
// MFMA clusters (2 independent blocks/SIMD = T5's regime).
// prep/gemm/merge_ln identical (proven).

#define CDIM 256
#define NPOS 4096
#define BATCH 4
#define EPSV 1e-5f

typedef _Float16 f16;
typedef __attribute__((ext_vector_type(8))) _Float16 f16x8;
typedef __attribute__((ext_vector_type(4))) float f32x4;
typedef __attribute__((ext_vector_type(16))) float f32x16;

#define WST       264   // f16; 528B = 33*16 -> b128-aligned rows
#define QK_STRIDE 264   // f16 K-tile rows
#define S_STRIDE  68    // f32; 272B = 17*16 (P f16 aliased in first 128B/row)
#define DQ_STRIDE 72
#define F_STRIDE  68    // merge kernel LDS stride (f32)

// LDS-only barrier: waves' prior LDS ops complete, global loads stay in
// flight (no vmcnt(0) drain). All three attn barriers guard LDS data only.
#define LBAR() asm volatile("s_waitcnt lgkmcnt(0)\n\ts_barrier" ::: "memory")

// MFMA 32x32x16 f16:
//   A: lane l holds A[m=l&31][k=(l>>5)*8+j]
//   B: lane l holds B[k=(l>>5)*8+j][n=l&31]
//   C/D: lane l, reg r -> col=l&31, row=(r&3)+8*(r>>2)+4*(l>>5)

static __device__ __forceinline__ f16x8 cvt8(const float* __restrict__ p) {
    float4 w0 = *(const float4*)p;
    float4 w1 = *(const float4*)(p + 4);
    f16x8 r;
    r[0] = (f16)w0.x; r[1] = (f16)w0.y; r[2] = (f16)w0.z; r[3] = (f16)w0.w;
    r[4] = (f16)w1.x; r[5] = (f16)w1.y; r[6] = (f16)w1.z; r[7] = (f16)w1.w;
    return r;
}

// ---------------------------------------------------------------------------
// prep: blocks 0..2047 transpose x1/x2 [C][N] fp32 -> [N][C] f16 (64x64 tiles);
// blocks 2048..2059 convert weights fp32 -> f16 [o][c].  (unchanged)
// ---------------------------------------------------------------------------
__global__ __launch_bounds__(256, 4) void prep_kernel(
    const float* __restrict__ x1, const float* __restrict__ x2,
    const float* __restrict__ qw, const float* __restrict__ kw,
    const float* __restrict__ vw,
    f16* __restrict__ X1T, f16* __restrict__ X2T, f16* __restrict__ W16)
{
    const int id = blockIdx.x;
    const int t  = threadIdx.x;
    if (id < 2048) {
        __shared__ f16 T[64 * 72];
        const float* xs = (id & 1) ? x2 : x1;
        f16* dst        = (id & 1) ? X2T : X1T;
        const int t2 = id >> 1;
        const int b  = t2 >> 8;
        const int rm = t2 & 255;
        const int c0 = (rm >> 6) * 64;
        const int n0 = (rm & 63) * 64;
        const float* src = xs + ((size_t)b * CDIM + c0) * NPOS + n0;
        const int rr = t >> 6, col = t & 63;
        #pragma unroll
        for (int j = 0; j < 16; ++j) {
            int row = rr + j * 4;
            T[col * 72 + row] = (f16)src[(size_t)row * NPOS + col];
        }
        __syncthreads();
        const int n = t >> 3, lc = (t & 7) * 8;
        f16* d0 = dst + ((size_t)b * NPOS + n0) * CDIM + c0;
        #pragma unroll
        for (int j = 0; j < 2; ++j) {
            int nn = n + j * 32;
            *(f16x8*)(d0 + (size_t)nn * CDIM + lc) = *(const f16x8*)&T[nn * 72 + lc];
        }
    } else {
        const int wblk = id - 2048;          // 0..11
        const int pr = wblk >> 2, h = wblk & 3;
        const float* W = (pr == 0 ? qw : pr == 1 ? kw : vw) + (size_t)h * 64 * CDIM;
        f16* D = W16 + (size_t)pr * CDIM * CDIM + (size_t)h * 64 * CDIM;
        #pragma unroll
        for (int i = 0; i < 8; ++i) {
            int g = t + i * 256;
            int row = g >> 5, col = (g & 31) * 8;
            *(f16x8*)(D + (size_t)row * CDIM + col) = cvt8(W + (size_t)row * CDIM + col);
        }
    }
}

// ---------------------------------------------------------------------------
// gemm: unchanged (proven correct). 768 blocks, weight quarters in LDS,
// split-k dual acc, LDS-assisted coalesced stores.
// ---------------------------------------------------------------------------
__global__ __launch_bounds__(256, 2) void gemm_kernel(
    const f16* __restrict__ X1T, const f16* __restrict__ X2T,
    const f16* __restrict__ W16,
    const float* __restrict__ qb, const float* __restrict__ kb,
    const float* __restrict__ vb,
    f16* __restrict__ Qg, f16* __restrict__ Kg, f16* __restrict__ Vg)
{
    __shared__ f16 Xs[64 * WST];
    __shared__ f16 Wh[64 * WST];
    __shared__ f16 Ds[64 * DQ_STRIDE];
    __shared__ float biasS[256];

    const int id = blockIdx.x;
    const int pr  = id >> 8;
    const int rem = id & 255;
    const int b   = rem >> 6;
    const int p0  = (rem & 63) << 6;
    const f16* XT = (pr == 0) ? X1T : X2T;
    const f16* Wp = W16 + (size_t)pr * CDIM * CDIM;
    const float* bias = pr == 0 ? qb : pr == 1 ? kb : vb;

    const int t = threadIdx.x, w = t >> 6, l = t & 63, lm = l & 31, lh = l >> 5;
    const int pt = w & 1, ot = w >> 1;

    biasS[t] = bias[t];
    #pragma unroll
    for (int it = 0; it < 8; ++it) {
        int p = w * 16 + it * 2 + lh;
        *(f16x8*)&Xs[p * WST + lm * 8] =
            *(const f16x8*)(XT + ((size_t)(b * NPOS + p0 + p)) * CDIM + lm * 8);
    }

    for (int q = 0; q < 4; ++q) {
        #pragma unroll
        for (int i = 0; i < 8; ++i) {
            int g = t + i * 256;
            int row = g >> 5, col = (g & 31) * 8;
            *(f16x8*)&Wh[row * WST + col] =
                *(const f16x8*)(Wp + (size_t)(q * 64 + row) * CDIM + col);
        }
        __syncthreads();

        f32x16 accA = {}, accB = {};
        #pragma unroll
        for (int ks = 0; ks < 16; ks += 2) {
            f16x8 x0 = *(const f16x8*)&Xs[(pt * 32 + lm) * WST + ks * 16 + lh * 8];
            f16x8 w0 = *(const f16x8*)&Wh[(ot * 32 + lm) * WST + ks * 16 + lh * 8];
            f16x8 x1v = *(const f16x8*)&Xs[(pt * 32 + lm) * WST + (ks + 1) * 16 + lh * 8];
            f16x8 w1 = *(const f16x8*)&Wh[(ot * 32 + lm) * WST + (ks + 1) * 16 + lh * 8];
            if (pr < 2) {
                accA = __builtin_amdgcn_mfma_f32_32x32x16_f16(x0, w0, accA, 0, 0, 0);
                accB = __builtin_amdgcn_mfma_f32_32x32x16_f16(x1v, w1, accB, 0, 0, 0);
            } else {
                accA = __builtin_amdgcn_mfma_f32_32x32x16_f16(w0, x0, accA, 0, 0, 0);
                accB = __builtin_amdgcn_mfma_f32_32x32x16_f16(w1, x1v, accB, 0, 0, 0);
            }
        }

        if (pr < 2) {
            int o_l = ot * 32 + lm;
            float bv = biasS[q * 64 + o_l];
            #pragma unroll
            for (int r = 0; r < 16; ++r) {
                int p_l = pt * 32 + (r & 3) + 8 * (r >> 2) + 4 * lh;
                Ds[p_l * DQ_STRIDE + o_l] = (f16)(accA[r] + accB[r] + bv);
            }
        } else {
            #pragma unroll
            for (int r = 0; r < 16; ++r) {
                int o_l = ot * 32 + (r & 3) + 8 * (r >> 2) + 4 * lh;
                Ds[o_l * DQ_STRIDE + pt * 32 + lm] =
                    (f16)(accA[r] + accB[r] + biasS[q * 64 + o_l]);
            }
        }
        __syncthreads();

        #pragma unroll
        for (int j = 0; j < 2; ++j) {
            int row = (t >> 3) + j * 32;
            int cc  = (t & 7) * 8;
            f16x8 vdat = *(const f16x8*)&Ds[row * DQ_STRIDE + cc];
            if (pr < 2) {
                f16* Out = (pr == 0) ? Qg : Kg;
                *(f16x8*)(Out + ((size_t)(b * NPOS + p0 + row)) * CDIM + q * 64 + cc) = vdat;
            } else {
                *(f16x8*)(Vg + ((size_t)(b * CDIM + q * 64 + row)) * NPOS + p0 + cc) = vdat;
            }
        }
        __syncthreads();
    }
}

// ---------------------------------------------------------------------------
// attn: grid 512, 256 thr = 4 waves, launch_bounds(256,2), 2 blocks/CU all
// co-resident, bijective XCD swizzle (each XCD's 64 blocks share one (b,half)
// K/V stream = 4MB = one L2). Per block: 32 key-chunks, K prefetch regs ->
// LDS commit with full-chunk prefetch window, LDS-only barriers (no vmcnt
// drain), dual-chain QK^T, setprio around MFMA clusters. LDS 51.2 KB.
// Emits partial F fp32 [bq][half][256c][64p].
// ---------------------------------------------------------------------------
__global__ __launch_bounds__(256, 2) void attn_kernel(
    const f16* __restrict__ Qg, const f16* __restrict__ Kg, const f16* __restrict__ Vg,
    float* __restrict__ Fp)
{
    __shared__ f16   Ks[64 * QK_STRIDE];  // 33792 B
    __shared__ float Ss[64 * S_STRIDE];   // 17408 B (P f16 aliased per-row)

    const int t    = threadIdx.x;
    const int L    = (int)((blockIdx.x & 7) * 64 + (blockIdx.x >> 3)); // XCD swizzle
    const int grp  = L >> 6;         // 0..7 = (b<<1 | half)
    const int b    = grp >> 1;
    const int half = grp & 1;
    const int qt   = L & 63;
    const int p0   = qt << 6;
    const int bq   = b * 64 + qt;
    const int w    = t >> 6;         // 0..3
    const int l    = t & 63;
    const int lm   = l & 31;
    const int lh   = l >> 5;
    const int spt  = w & 1;          // wave's S tile: query-tile spt, key-tile skt
    const int skt  = w >> 1;

    // Q fragments for this wave's query-tile (registers, all chunks)
    f16x8 qf[16];
    {
        const f16* qptr = Qg + (size_t)(b * NPOS + p0 + spt * 32 + lm) * CDIM + lh * 8;
        #pragma unroll
        for (int ks = 0; ks < 16; ++ks) qf[ks] = *(const f16x8*)(qptr + ks * 16);
    }

    // K prefetch registers: this block's chunk stream = half*32 .. half*32+31
    const int kr = t >> 5, koff = (t & 31) * 8;
    f16x8 kreg[8];
    auto issue_k = [&](int ch) {
        const int i0 = ch * 64;
        #pragma unroll
        for (int r = 0; r < 8; ++r)
            kreg[r] = *(const f16x8*)(Kg + (size_t)(b * NPOS + i0 + r * 8 + kr) * CDIM + koff);
    };
    issue_k(half * 32);

    // V fragment bases: wave's c-strip = w*64 + {0,32}
    const f16* vb0 = Vg + (size_t)(b * CDIM + w * 64 + lm) * NPOS;
    const f16* vb1 = Vg + (size_t)(b * CDIM + w * 64 + 32 + lm) * NPOS;

    f16* Pal = (f16*)&Ss[0];          // P alias: row r at f16 offset r*136

    f32x16 facc[4] = {};      // per-wave F acc: [i=c-tile(2)][j=p-tile(2)]

    for (int it = 0; it < 32; ++it) {
        const int i0 = (half * 32 + it) * 64;

        // commit prefetched K to LDS (ds_write reads kreg at issue), then
        // immediately issue next chunk's K loads -> full-chunk latency window
        #pragma unroll
        for (int r = 0; r < 8; ++r)
            *(f16x8*)&Ks[(r * 8 + kr) * QK_STRIDE + koff] = kreg[r];
        if (it < 31) issue_k(half * 32 + it + 1);
        LBAR();   // A: Ks ready; prev P reads done (K/V global loads in flight)

        // issue this chunk's V fragment loads (consumed at PV, counted vmcnt)
        f16x8 vf0[4], vf1[4];
        #pragma unroll
        for (int ks = 0; ks < 4; ++ks) {
            vf0[ks] = *(const f16x8*)(vb0 + i0 + ks * 16 + lh * 8);
            vf1[ks] = *(const f16x8*)(vb1 + i0 + ks * 16 + lh * 8);
        }

        // S = Q K^T  (two independent accumulator chains, dep depth 8)
        f32x16 sacc0 = {}, sacc1 = {};
        __builtin_amdgcn_s_setprio(1);
        #pragma unroll
        for (int ks = 0; ks < 16; ks += 2) {
            f16x8 b0 = *(const f16x8*)&Ks[(skt * 32 + lm) * QK_STRIDE + ks * 16 + lh * 8];
            f16x8 b1 = *(const f16x8*)&Ks[(skt * 32 + lm) * QK_STRIDE + (ks + 1) * 16 + lh * 8];
            sacc0 = __builtin_amdgcn_mfma_f32_32x32x16_f16(qf[ks], b0, sacc0, 0, 0, 0);
            sacc1 = __builtin_amdgcn_mfma_f32_32x32x16_f16(qf[ks + 1], b1, sacc1, 0, 0, 0);
        }
        __builtin_amdgcn_s_setprio(0);
        f32x16 sacc = sacc0 + sacc1;
        #pragma unroll
        for (int r = 0; r < 16; ++r) {
            int row = (r & 3) + 8 * (r >> 2) + 4 * lh;
            Ss[(spt * 32 + row) * S_STRIDE + skt * 32 + lm] = sacc[r];
        }
        LBAR();   // B: Ss ready (V loads still in flight)

        // softmax per row: 4 threads/row x 16 elems; P written in place
        {
            const int r  = t >> 2;
            const int sg = (t & 3) * 16;
            const float* srow = &Ss[r * S_STRIDE + sg];
            float v[16];
            f32x4 a0 = *(const f32x4*)(srow);
            f32x4 a1 = *(const f32x4*)(srow + 4);
            f32x4 a2 = *(const f32x4*)(srow + 8);
            f32x4 a3 = *(const f32x4*)(srow + 12);
            v[0]=a0[0]; v[1]=a0[1]; v[2]=a0[2]; v[3]=a0[3];
            v[4]=a1[0]; v[5]=a1[1]; v[6]=a1[2]; v[7]=a1[3];
            v[8]=a2[0]; v[9]=a2[1]; v[10]=a2[2]; v[11]=a2[3];
            v[12]=a3[0]; v[13]=a3[1]; v[14]=a3[2]; v[15]=a3[3];
            float m = v[0];
            #pragma unroll
            for (int i = 1; i < 16; ++i) m = fmaxf(m, v[i]);
            m = fmaxf(m, __shfl_xor(m, 1));
            m = fmaxf(m, __shfl_xor(m, 2));
            float s = 0.f;
            #pragma unroll
            for (int i = 0; i < 16; ++i) { float e = __expf(v[i] - m); v[i] = e; s += e; }
            s += __shfl_xor(s, 1);
            s += __shfl_xor(s, 2);
            float inv = __builtin_amdgcn_rcpf(s);
            f16x8 h0, h1;
            #pragma unroll
            for (int i = 0; i < 8; ++i) { h0[i] = (f16)(v[i] * inv); h1[i] = (f16)(v[i + 8] * inv); }
            // in-place: same-wave read-before-write per row, safe
            *(f16x8*)&Pal[r * 136 + sg]     = h0;
            *(f16x8*)&Pal[r * 136 + sg + 8] = h1;
        }
        LBAR();   // C: P ready (K prefetch still in flight)

        // F += V * P^T
        __builtin_amdgcn_s_setprio(1);
        #pragma unroll
        for (int ks = 0; ks < 4; ++ks) {
            f16x8 bp0 = *(const f16x8*)&Pal[lm * 136 + ks * 16 + lh * 8];
            f16x8 bp1 = *(const f16x8*)&Pal[(32 + lm) * 136 + ks * 16 + lh * 8];
            facc[0] = __builtin_amdgcn_mfma_f32_32x32x16_f16(vf0[ks], bp0, facc[0], 0, 0, 0);
            facc[1] = __builtin_amdgcn_mfma_f32_32x32x16_f16(vf0[ks], bp1, facc[1], 0, 0, 0);
            facc[2] = __builtin_amdgcn_mfma_f32_32x32x16_f16(vf1[ks], bp0, facc[2], 0, 0, 0);
            facc[3] = __builtin_amdgcn_mfma_f32_32x32x16_f16(vf1[ks], bp1, facc[3], 0, 0, 0);
        }
        __builtin_amdgcn_s_setprio(0);
    }

    // partial F out: Fp[bq][half][c][p] fp32, lanes lm -> consecutive p
    float* dst = Fp + ((size_t)bq * 2 + half) * (CDIM * 64);
    #pragma unroll
    for (int ii = 0; ii < 2; ++ii)
        #pragma unroll
        for (int jj = 0; jj < 2; ++jj)
            #pragma unroll
            for (int r = 0; r < 16; ++r) {
                int c = w * 64 + ii * 32 + (r & 3) + 8 * (r >> 2) + 4 * lh;
                int p = jj * 32 + lm;
                dst[c * 64 + p] = facc[ii * 2 + jj][r];
            }
}

// ---------------------------------------------------------------------------
// merge_ln: grid 256 = (b<<6 | qtile), 256 thr. Sums the 2 half-partials
// into LDS, computes per-position mean/var over channels, writes normalized
// output. Memory-bound (~48 MB traffic). (unchanged, proven correct)
// ---------------------------------------------------------------------------
__global__ __launch_bounds__(256, 2) void merge_ln_kernel(
    const float* __restrict__ Fp, const float* __restrict__ ln_w,
    const float* __restrict__ ln_b, float* __restrict__ out)
{
    __shared__ float Fs[256 * F_STRIDE];          // 69632 B
    __shared__ float redS[16 * 64], redQ[16 * 64];
    __shared__ float lnw_s[256], lnb_s[256];
    __shared__ float mu_s[64], rs_s[64];

    const int t  = threadIdx.x;
    const int bq = blockIdx.x;
    const int b  = bq >> 6;
    const int p0 = (bq & 63) << 6;

    lnw_s[t] = ln_w[t]; lnb_s[t] = ln_b[t];

    const int pb = (t & 15) * 4;      // 4 consecutive positions
    const int cg = t >> 4;            // 16-channel group
    const float* base = Fp + (size_t)bq * 2 * (CDIM * 64);

    f32x4 s4 = {}, q4 = {};
    #pragma unroll 4
    for (int ci = 0; ci < 16; ++ci) {
        int c = cg * 16 + ci;
        size_t off = (size_t)c * 64 + pb;
        f32x4 v = *(const f32x4*)(base + off);
        v += *(const f32x4*)(base + (size_t)(CDIM * 64) + off);
        *(f32x4*)&Fs[c * F_STRIDE + pb] = v;
        s4 += v; q4 += v * v;
    }
    #pragma unroll
    for (int k2 = 0; k2 < 4; ++k2) {
        redS[cg * 64 + pb + k2] = s4[k2];
        redQ[cg * 64 + pb + k2] = q4[k2];
    }
    __syncthreads();
    if (t < 64) {
        float ss = 0.f, qq = 0.f;
        #pragma unroll
        for (int g2 = 0; g2 < 16; ++g2) { ss += redS[g2 * 64 + t]; qq += redQ[g2 * 64 + t]; }
        float mean = ss * (1.0f / 256.0f);
        float var  = qq * (1.0f / 256.0f) - mean * mean;
        mu_s[t] = mean;
        rs_s[t] = rsqrtf(var + EPSV);
    }
    __syncthreads();
    const int p   = t & 63;
    const int cg2 = t >> 6;
    const float mu = mu_s[p], rs = rs_s[p];
    float* dst = out + (size_t)b * CDIM * NPOS + p0 + p;
    #pragma unroll 4
    for (int ci = 0; ci < 64; ++ci) {
        int c = cg2 * 64 + ci;
        dst[(size_t)c * NPOS] = (Fs[c * F_STRIDE + p] - mu) * rs * lnw_s[c] + lnb_s[c];
    }
}

// ---------------------------------------------------------------------------
extern "C" void kernel_launch(void* const* d_in, const int* in_sizes, int n_in,
                              void* d_out, int out_size, void* d_ws, size_t ws_size,
                              hipStream_t stream)
{
    const float* x1  = (const float*)d_in[0];
    const float* x2  = (const float*)d_in[1];
    const float* qw  = (const float*)d_in[2];
    const float* qb  = (const float*)d_in[3];
    const float* kw  = (const float*)d_in[4];
    const float* kb  = (const float*)d_in[5];
    const float* vw  = (const float*)d_in[6];
    const float* vb  = (const float*)d_in[7];
    const float* lnw = (const float*)d_in[8];
    const float* lnb = (const float*)d_in[9];

    const size_t tsz = (size_t)BATCH * NPOS * CDIM;
    f16* Qg  = (f16*)d_ws;
    f16* Kg  = Qg + tsz;
    f16* Vg  = Kg + tsz;
    f16* X1T = Vg + tsz;          // dead after gemm
    f16* X2T = X1T + tsz;         // dead after gemm
    f16* W16 = X2T + tsz;         // dead after gemm
    // Fp (32 MB fp32) reuses the X1T/X2T/W16 region (all dead once attn runs).
    float* Fp = (float*)X1T;      // total ws footprint: 24 MB (QKV) + 32 MB

    prep_kernel<<<2060, 256, 0, stream>>>(x1, x2, qw, kw, vw, X1T, X2T, W16);
    gemm_kernel<<<768, 256, 0, stream>>>(X1T, X2T, W16, qb, kb, vb, Qg, Kg, Vg);
    attn_kernel<<<512, 256, 0, stream>>>(Qg, Kg, Vg, Fp);
    merge_ln_kernel<<<256, 256, 0, stream>>>(Fp, lnw, lnb, (float*)d_out);
}

// Round 5
// 217.054 us; speedup vs baseline: 1.6226x; 1.0036x over previous
//
#include <hip/hip_runtime.h>

// B=4, C=256, H=W=64 (N=4096). QKV 1x1conv -> spatial attention (softmax over
// j only => independent per-64-key-chunk softmax) -> channel LayerNorm.
// f16 MFMA 32x32x16, fp32 accumulation.
//
// R11: attn restructured around two fixes, structure (grid 512, 2 blocks/CU,
// XCD swizzle, (256,2)) unchanged:
//  1) Swapped QK^T (T12): st = mfma(Kfrag, Qfrag) -> S^T[key][p]; A/B frags
//     have identical lane layouts so Ks reads and qf registers are unchanged.
//     Softmax becomes in-register (15 ops + shfl_xor(32) + tiny LDS exchange
//     between the skt-wave pair, LSE merge). S-f32 LDS buffer deleted; only
//     a 9KB f16 P tile is written (4x ds_write_b64/lane).
//  2) V staged to LDS Vs[c][j] (stride 72) via reg-prefetch (issue early /
//     commit late): staging reads are 128B-contiguous per c-row instead of
//     the old PV loads' 32-distinct-lines-per-instr scatter (4x L2 request
//     amplification). PV A-frags = contiguous ds_read_b128 from Vs.
// LDS 80896 B (Ks 33792 + Vs 36864 + P 9216 + Red 1024) = 2 blocks/CU.
// QK single acc chain (register budget ~235 < 256, no spill).
// prep/gemm/merge_ln identical (proven).

#define CDIM 256
#define NPOS 4096
#define BATCH 4
#define EPSV 1e-5f

typedef _Float16 f16;
typedef __attribute__((ext_vector_type(4))) _Float16 f16x4;
typedef __attribute__((ext_vector_type(8))) _Float16 f16x8;
typedef __attribute__((ext_vector_type(4))) float f32x4;
typedef __attribute__((ext_vector_type(16))) float f32x16;

#define WST       264   // f16; 528B = 33*16 -> b128-aligned rows
#define QK_STRIDE 264   // f16 K-tile rows (512B data + pad, 16B-aligned)
#define V_STRIDE  72    // f16 Vs/P rows; 144B = 9*16 -> b128-aligned, bank-spread
#define DQ_STRIDE 72
#define F_STRIDE  68    // merge kernel LDS stride (f32)

// LDS-only barrier: prior LDS ops complete, global loads stay in flight.
#define LBAR() asm volatile("s_waitcnt lgkmcnt(0)\n\ts_barrier" ::: "memory")

// MFMA 32x32x16 f16:
//   A: lane l holds A[m=l&31][k=(l>>5)*8+j]
//   B: lane l holds B[k=(l>>5)*8+j][n=l&31]   (same register layout as A!)
//   C/D: lane l, reg r -> row m=(r&3)+8*(r>>2)+4*(l>>5), col n=l&31

static __device__ __forceinline__ f16x8 cvt8(const float* __restrict__ p) {
    float4 w0 = *(const float4*)p;
    float4 w1 = *(const float4*)(p + 4);
    f16x8 r;
    r[0] = (f16)w0.x; r[1] = (f16)w0.y; r[2] = (f16)w0.z; r[3] = (f16)w0.w;
    r[4] = (f16)w1.x; r[5] = (f16)w1.y; r[6] = (f16)w1.z; r[7] = (f16)w1.w;
    return r;
}

// ---------------------------------------------------------------------------
// prep: blocks 0..2047 transpose x1/x2 [C][N] fp32 -> [N][C] f16 (64x64 tiles);
// blocks 2048..2059 convert weights fp32 -> f16 [o][c].  (unchanged)
// ---------------------------------------------------------------------------
__global__ __launch_bounds__(256, 4) void prep_kernel(
    const float* __restrict__ x1, const float* __restrict__ x2,
    const float* __restrict__ qw, const float* __restrict__ kw,
    const float* __restrict__ vw,
    f16* __restrict__ X1T, f16* __restrict__ X2T, f16* __restrict__ W16)
{
    const int id = blockIdx.x;
    const int t  = threadIdx.x;
    if (id < 2048) {
        __shared__ f16 T[64 * 72];
        const float* xs = (id & 1) ? x2 : x1;
        f16* dst        = (id & 1) ? X2T : X1T;
        const int t2 = id >> 1;
        const int b  = t2 >> 8;
        const int rm = t2 & 255;
        const int c0 = (rm >> 6) * 64;
        const int n0 = (rm & 63) * 64;
        const float* src = xs + ((size_t)b * CDIM + c0) * NPOS + n0;
        const int rr = t >> 6, col = t & 63;
        #pragma unroll
        for (int j = 0; j < 16; ++j) {
            int row = rr + j * 4;
            T[col * 72 + row] = (f16)src[(size_t)row * NPOS + col];
        }
        __syncthreads();
        const int n = t >> 3, lc = (t & 7) * 8;
        f16* d0 = dst + ((size_t)b * NPOS + n0) * CDIM + c0;
        #pragma unroll
        for (int j = 0; j < 2; ++j) {
            int nn = n + j * 32;
            *(f16x8*)(d0 + (size_t)nn * CDIM + lc) = *(const f16x8*)&T[nn * 72 + lc];
        }
    } else {
        const int wblk = id - 2048;          // 0..11
        const int pr = wblk >> 2, h = wblk & 3;
        const float* W = (pr == 0 ? qw : pr == 1 ? kw : vw) + (size_t)h * 64 * CDIM;
        f16* D = W16 + (size_t)pr * CDIM * CDIM + (size_t)h * 64 * CDIM;
        #pragma unroll
        for (int i = 0; i < 8; ++i) {
            int g = t + i * 256;
            int row = g >> 5, col = (g & 31) * 8;
            *(f16x8*)(D + (size_t)row * CDIM + col) = cvt8(W + (size_t)row * CDIM + col);
        }
    }
}

// ---------------------------------------------------------------------------
// gemm: unchanged (proven correct). 768 blocks, weight quarters in LDS,
// split-k dual acc, LDS-assisted coalesced stores.
// ---------------------------------------------------------------------------
__global__ __launch_bounds__(256, 2) void gemm_kernel(
    const f16* __restrict__ X1T, const f16* __restrict__ X2T,
    const f16* __restrict__ W16,
    const float* __restrict__ qb, const float* __restrict__ kb,
    const float* __restrict__ vb,
    f16* __restrict__ Qg, f16* __restrict__ Kg, f16* __restrict__ Vg)
{
    __shared__ f16 Xs[64 * WST];
    __shared__ f16 Wh[64 * WST];
    __shared__ f16 Ds[64 * DQ_STRIDE];
    __shared__ float biasS[256];

    const int id = blockIdx.x;
    const int pr  = id >> 8;
    const int rem = id & 255;
    const int b   = rem >> 6;
    const int p0  = (rem & 63) << 6;
    const f16* XT = (pr == 0) ? X1T : X2T;
    const f16* Wp = W16 + (size_t)pr * CDIM * CDIM;
    const float* bias = pr == 0 ? qb : pr == 1 ? kb : vb;

    const int t = threadIdx.x, w = t >> 6, l = t & 63, lm = l & 31, lh = l >> 5;
    const int pt = w & 1, ot = w >> 1;

    biasS[t] = bias[t];
    #pragma unroll
    for (int it = 0; it < 8; ++it) {
        int p = w * 16 + it * 2 + lh;
        *(f16x8*)&Xs[p * WST + lm * 8] =
            *(const f16x8*)(XT + ((size_t)(b * NPOS + p0 + p)) * CDIM + lm * 8);
    }

    for (int q = 0; q < 4; ++q) {
        #pragma unroll
        for (int i = 0; i < 8; ++i) {
            int g = t + i * 256;
            int row = g >> 5, col = (g & 31) * 8;
            *(f16x8*)&Wh[row * WST + col] =
                *(const f16x8*)(Wp + (size_t)(q * 64 + row) * CDIM + col);
        }
        __syncthreads();

        f32x16 accA = {}, accB = {};
        #pragma unroll
        for (int ks = 0; ks < 16; ks += 2) {
            f16x8 x0 = *(const f16x8*)&Xs[(pt * 32 + lm) * WST + ks * 16 + lh * 8];
            f16x8 w0 = *(const f16x8*)&Wh[(ot * 32 + lm) * WST + ks * 16 + lh * 8];
            f16x8 x1v = *(const f16x8*)&Xs[(pt * 32 + lm) * WST + (ks + 1) * 16 + lh * 8];
            f16x8 w1 = *(const f16x8*)&Wh[(ot * 32 + lm) * WST + (ks + 1) * 16 + lh * 8];
            if (pr < 2) {
                accA = __builtin_amdgcn_mfma_f32_32x32x16_f16(x0, w0, accA, 0, 0, 0);
                accB = __builtin_amdgcn_mfma_f32_32x32x16_f16(x1v, w1, accB, 0, 0, 0);
            } else {
                accA = __builtin_amdgcn_mfma_f32_32x32x16_f16(w0, x0, accA, 0, 0, 0);
                accB = __builtin_amdgcn_mfma_f32_32x32x16_f16(w1, x1v, accB, 0, 0, 0);
            }
        }

        if (pr < 2) {
            int o_l = ot * 32 + lm;
            float bv = biasS[q * 64 + o_l];
            #pragma unroll
            for (int r = 0; r < 16; ++r) {
                int p_l = pt * 32 + (r & 3) + 8 * (r >> 2) + 4 * lh;
                Ds[p_l * DQ_STRIDE + o_l] = (f16)(accA[r] + accB[r] + bv);
            }
        } else {
            #pragma unroll
            for (int r = 0; r < 16; ++r) {
                int o_l = ot * 32 + (r & 3) + 8 * (r >> 2) + 4 * lh;
                Ds[o_l * DQ_STRIDE + pt * 32 + lm] =
                    (f16)(accA[r] + accB[r] + biasS[q * 64 + o_l]);
            }
        }
        __syncthreads();

        #pragma unroll
        for (int j = 0; j < 2; ++j) {
            int row = (t >> 3) + j * 32;
            int cc  = (t & 7) * 8;
            f16x8 vdat = *(const f16x8*)&Ds[row * DQ_STRIDE + cc];
            if (pr < 2) {
                f16* Out = (pr == 0) ? Qg : Kg;
                *(f16x8*)(Out + ((size_t)(b * NPOS + p0 + row)) * CDIM + q * 64 + cc) = vdat;
            } else {
                *(f16x8*)(Vg + ((size_t)(b * CDIM + q * 64 + row)) * NPOS + p0 + cc) = vdat;
            }
        }
        __syncthreads();
    }
}

// ---------------------------------------------------------------------------
// attn: grid 512, 256 thr = 4 waves, (256,2), 2 blocks/CU co-resident,
// bijective XCD swizzle. Per chunk: K+V reg-prefetch -> LDS commit; swapped
// QK^T (S^T in registers); in-register softmax with LSE cross-wave merge;
// P f16 tile (9KB) -> LDS; PV from Vs+P ds_read_b128. 3 LDS-only barriers.
// Emits partial F fp32 [bq][half][256c][64p].
// ---------------------------------------------------------------------------
__global__ __launch_bounds__(256, 2) void attn_kernel(
    const f16* __restrict__ Qg, const f16* __restrict__ Kg, const f16* __restrict__ Vg,
    float* __restrict__ Fp)
{
    __shared__ f16   Ks[64 * QK_STRIDE];   // 33792 B  [key][c]
    __shared__ f16   Vs[256 * V_STRIDE];   // 36864 B  [c][j]
    __shared__ f16   Pl[64 * V_STRIDE];    //  9216 B  [p][key]
    __shared__ float RedM[2][64], RedS[2][64];  // 1024 B

    const int t    = threadIdx.x;
    const int L    = (int)((blockIdx.x & 7) * 64 + (blockIdx.x >> 3)); // XCD swizzle
    const int grp  = L >> 6;         // 0..7 = (b<<1 | half)
    const int b    = grp >> 1;
    const int half = grp & 1;
    const int qt   = L & 63;
    const int p0   = qt << 6;
    const int bq   = b * 64 + qt;
    const int w    = t >> 6;         // 0..3
    const int l    = t & 63;
    const int lm   = l & 31;
    const int lh   = l >> 5;
    const int spt  = w & 1;          // wave's p-tile
    const int skt  = w >> 1;         // wave's key-tile

    // Q fragments (used as MFMA B-operand; layout identical to A-operand)
    f16x8 qf[16];
    {
        const f16* qptr = Qg + (size_t)(b * NPOS + p0 + spt * 32 + lm) * CDIM + lh * 8;
        #pragma unroll
        for (int ks = 0; ks < 16; ++ks) qf[ks] = *(const f16x8*)(qptr + ks * 16);
    }

    // K prefetch registers (rows coalesced from Kg[n][c])
    const int kr = t >> 5, koff = (t & 31) * 8;
    f16x8 kreg[8];
    auto issue_k = [&](int ch) {
        const int i0 = ch * 64;
        #pragma unroll
        for (int r = 0; r < 8; ++r)
            kreg[r] = *(const f16x8*)(Kg + (size_t)(b * NPOS + i0 + r * 8 + kr) * CDIM + koff);
    };

    // V prefetch registers (128B-contiguous runs per c-row from Vg[c][n])
    const int vr = t >> 3;           // c row within each 32-row group
    const int vc = (t & 7) * 8;      // halfword col within chunk
    f16x8 vreg[8];
    auto issue_v = [&](int ch) {
        const int i0 = ch * 64;
        #pragma unroll
        for (int i = 0; i < 8; ++i)
            vreg[i] = *(const f16x8*)(Vg + (size_t)(b * CDIM + i * 32 + vr) * NPOS + i0 + vc);
    };

    issue_k(half * 32);
    issue_v(half * 32);

    f32x16 facc[4] = {};      // per-wave F acc: [ci=c-subtile(2)][pj=p-tile(2)]

    for (int it = 0; it < 32; ++it) {
        const int ch = half * 32 + it;

        // commit prefetched K to LDS, then issue next chunk's K loads
        #pragma unroll
        for (int r = 0; r < 8; ++r)
            *(f16x8*)&Ks[(r * 8 + kr) * QK_STRIDE + koff] = kreg[r];
        if (it < 31) issue_k(ch + 1);
        LBAR();   // A: Ks ready; prev PV's Vs/Pl reads done

        // commit prefetched V to LDS, then issue next chunk's V loads
        #pragma unroll
        for (int i = 0; i < 8; ++i)
            *(f16x8*)&Vs[(i * 32 + vr) * V_STRIDE + vc] = vreg[i];
        if (it < 31) issue_v(ch + 1);

        // S^T = K Q^T : D[m=key][n=p]; lane holds S^T[16 keys][p=spt*32+lm]
        f32x16 st = {};
        __builtin_amdgcn_s_setprio(1);
        #pragma unroll
        for (int ks = 0; ks < 16; ++ks) {
            f16x8 kf = *(const f16x8*)&Ks[(skt * 32 + lm) * QK_STRIDE + ks * 16 + lh * 8];
            st = __builtin_amdgcn_mfma_f32_32x32x16_f16(kf, qf[ks], st, 0, 0, 0);
        }
        __builtin_amdgcn_s_setprio(0);

        // in-register softmax over this key-tile (32 keys: 16 own + lh-partner)
        float mx = st[0];
        #pragma unroll
        for (int r = 1; r < 16; ++r) mx = fmaxf(mx, st[r]);
        mx = fmaxf(mx, __shfl_xor(mx, 32));
        float ss = 0.f;
        #pragma unroll
        for (int r = 0; r < 16; ++r) {
            float e = __expf(st[r] - mx);
            st[r] = e;
            ss += e;
        }
        ss += __shfl_xor(ss, 32);
        if (lh == 0) { RedM[skt][spt * 32 + lm] = mx; RedS[skt][spt * 32 + lm] = ss; }
        LBAR();   // B: Red exchange ready

        // LSE merge with partner key-tile wave -> full 64-key softmax
        float mo = RedM[skt ^ 1][spt * 32 + lm];
        float so = RedS[skt ^ 1][spt * 32 + lm];
        float M  = fmaxf(mx, mo);
        float S  = ss * __expf(mx - M) + so * __expf(mo - M);
        float scale = __expf(mx - M) * __builtin_amdgcn_rcpf(S);

        // P[key][p] f16 -> Pl[p][key]; lane's 16 keys = 4 runs of 4 consecutive
        #pragma unroll
        for (int rq = 0; rq < 4; ++rq) {
            f16x4 pk;
            #pragma unroll
            for (int q2 = 0; q2 < 4; ++q2) pk[q2] = (f16)(st[rq * 4 + q2] * scale);
            *(f16x4*)&Pl[(spt * 32 + lm) * V_STRIDE + skt * 32 + rq * 8 + lh * 4] = pk;
        }
        LBAR();   // C: Pl ready; Vs commits drained

        // F += V P : D[m=c][n=p]; A=Vs rows, B=Pl rows (both b128-contiguous)
        __builtin_amdgcn_s_setprio(1);
        #pragma unroll
        for (int kb = 0; kb < 4; ++kb) {
            f16x8 pf0 = *(const f16x8*)&Pl[lm * V_STRIDE + kb * 16 + lh * 8];
            f16x8 pf1 = *(const f16x8*)&Pl[(32 + lm) * V_STRIDE + kb * 16 + lh * 8];
            f16x8 va0 = *(const f16x8*)&Vs[(w * 64 + lm) * V_STRIDE + kb * 16 + lh * 8];
            f16x8 va1 = *(const f16x8*)&Vs[(w * 64 + 32 + lm) * V_STRIDE + kb * 16 + lh * 8];
            facc[0] = __builtin_amdgcn_mfma_f32_32x32x16_f16(va0, pf0, facc[0], 0, 0, 0);
            facc[1] = __builtin_amdgcn_mfma_f32_32x32x16_f16(va0, pf1, facc[1], 0, 0, 0);
            facc[2] = __builtin_amdgcn_mfma_f32_32x32x16_f16(va1, pf0, facc[2], 0, 0, 0);
            facc[3] = __builtin_amdgcn_mfma_f32_32x32x16_f16(va1, pf1, facc[3], 0, 0, 0);
        }
        __builtin_amdgcn_s_setprio(0);
    }

    // partial F out: Fp[bq][half][c][p] fp32 (identical layout to R10)
    float* dst = Fp + ((size_t)bq * 2 + half) * (CDIM * 64);
    #pragma unroll
    for (int ii = 0; ii < 2; ++ii)
        #pragma unroll
        for (int jj = 0; jj < 2; ++jj)
            #pragma unroll
            for (int r = 0; r < 16; ++r) {
                int c = w * 64 + ii * 32 + (r & 3) + 8 * (r >> 2) + 4 * lh;
                int p = jj * 32 + lm;
                dst[c * 64 + p] = facc[ii * 2 + jj][r];
            }
}

// ---------------------------------------------------------------------------
// merge_ln: grid 256 = (b<<6 | qtile), 256 thr. Sums the 2 half-partials
// into LDS, computes per-position mean/var over channels, writes normalized
// output. Memory-bound (~48 MB traffic). (unchanged, proven correct)
// ---------------------------------------------------------------------------
__global__ __launch_bounds__(256, 2) void merge_ln_kernel(
    const float* __restrict__ Fp, const float* __restrict__ ln_w,
    const float* __restrict__ ln_b, float* __restrict__ out)
{
    __shared__ float Fs[256 * F_STRIDE];          // 69632 B
    __shared__ float redS[16 * 64], redQ[16 * 64];
    __shared__ float lnw_s[256], lnb_s[256];
    __shared__ float mu_s[64], rs_s[64];

    const int t  = threadIdx.x;
    const int bq = blockIdx.x;
    const int b  = bq >> 6;
    const int p0 = (bq & 63) << 6;

    lnw_s[t] = ln_w[t]; lnb_s[t] = ln_b[t];

    const int pb = (t & 15) * 4;      // 4 consecutive positions
    const int cg = t >> 4;            // 16-channel group
    const float* base = Fp + (size_t)bq * 2 * (CDIM * 64);

    f32x4 s4 = {}, q4 = {};
    #pragma unroll 4
    for (int ci = 0; ci < 16; ++ci) {
        int c = cg * 16 + ci;
        size_t off = (size_t)c * 64 + pb;
        f32x4 v = *(const f32x4*)(base + off);
        v += *(const f32x4*)(base + (size_t)(CDIM * 64) + off);
        *(f32x4*)&Fs[c * F_STRIDE + pb] = v;
        s4 += v; q4 += v * v;
    }
    #pragma unroll
    for (int k2 = 0; k2 < 4; ++k2) {
        redS[cg * 64 + pb + k2] = s4[k2];
        redQ[cg * 64 + pb + k2] = q4[k2];
    }
    __syncthreads();
    if (t < 64) {
        float ss = 0.f, qq = 0.f;
        #pragma unroll
        for (int g2 = 0; g2 < 16; ++g2) { ss += redS[g2 * 64 + t]; qq += redQ[g2 * 64 + t]; }
        float mean = ss * (1.0f / 256.0f);
        float var  = qq * (1.0f / 256.0f) - mean * mean;
        mu_s[t] = mean;
        rs_s[t] = rsqrtf(var + EPSV);
    }
    __syncthreads();
    const int p   = t & 63;
    const int cg2 = t >> 6;
    const float mu = mu_s[p], rs = rs_s[p];
    float* dst = out + (size_t)b * CDIM * NPOS + p0 + p;
    #pragma unroll 4
    for (int ci = 0; ci < 64; ++ci) {
        int c = cg2 * 64 + ci;
        dst[(size_t)c * NPOS] = (Fs[c * F_STRIDE + p] - mu) * rs * lnw_s[c] + lnb_s[c];
    }
}

// ---------------------------------------------------------------------------
extern "C" void kernel_launch(void* const* d_in, const int* in_sizes, int n_in,
                              void* d_out, int out_size, void* d_ws, size_t ws_size,
                              hipStream_t stream)
{
    const float* x1  = (const float*)d_in[0];
    const float* x2  = (const float*)d_in[1];
    const float* qw  = (const float*)d_in[2];
    const float* qb  = (const float*)d_in[3];
    const float* kw  = (const float*)d_in[4];
    const float* kb  = (const float*)d_in[5];
    const float* vw  = (const float*)d_in[6];
    const float* vb  = (const float*)d_in[7];
    const float* lnw = (const float*)d_in[8];
    const float* lnb = (const float*)d_in[9];

    const size_t tsz = (size_t)BATCH * NPOS * CDIM;
    f16* Qg  = (f16*)d_ws;
    f16* Kg  = Qg + tsz;
    f16* Vg  = Kg + tsz;
    f16* X1T = Vg + tsz;          // dead after gemm
    f16* X2T = X1T + tsz;         // dead after gemm
    f16* W16 = X2T + tsz;         // dead after gemm
    // Fp (32 MB fp32) reuses the X1T/X2T/W16 region (all dead once attn runs).
    float* Fp = (float*)X1T;      // total ws footprint: 24 MB (QKV) + 32 MB

    prep_kernel<<<2060, 256, 0, stream>>>(x1, x2, qw, kw, vw, X1T, X2T, W16);
    gemm_kernel<<<768, 256, 0, stream>>>(X1T, X2T, W16, qb, kb, vb, Qg, Kg, Vg);
    attn_kernel<<<512, 256, 0, stream>>>(Qg, Kg, Vg, Fp);
    merge_ln_kernel<<<256, 256, 0, stream>>>(Fp, lnw, lnb, (float*)d_out);
}